// Round 1
// baseline (2860.664 us; speedup 1.0000x reference)
//
#include <hip/hip_runtime.h>

// GATv2 GNN classifier, fp32 throughout.
// Pipeline per layer: gemm(xl), gemm(xr) -> edge logits + atomicMax segmax
// -> exp + atomicAdd denom -> weighted scatter-add aggregate -> node epilogue.
// Then global mean pool (atomics) + 2-layer MLP.

// ---------------- float atomic max (signed-max / unsigned-min trick) -------
__device__ inline void atomicMaxFloat(float* addr, float val) {
    if (val >= 0.f) {
        atomicMax((int*)addr, __float_as_int(val));
    } else {
        atomicMin((unsigned int*)addr, __float_as_uint(val));
    }
}

// ---------------- GEMM: C[M,N] = A[M,K] * B[K,N] + bias[N] ----------------
// 64x64 tile, 256 threads, 4x4 microtile, BK=16.
__global__ __launch_bounds__(256) void gemm_bias(
    const float* __restrict__ A, const float* __restrict__ B,
    const float* __restrict__ bias, float* __restrict__ C,
    int M, int N, int K)
{
    __shared__ float As[16][65];
    __shared__ float Bs[16][65];
    const int row0 = blockIdx.y * 64;
    const int col0 = blockIdx.x * 64;
    const int t  = threadIdx.x;
    const int tx = t & 15;
    const int ty = t >> 4;
    float acc[4][4] = {};

    for (int k0 = 0; k0 < K; k0 += 16) {
        #pragma unroll
        for (int i = 0; i < 4; ++i) {
            int idx = t + i * 256;          // 0..1023 over 64x16 A tile
            int r = idx >> 4, c = idx & 15;
            float v = 0.f;
            if (row0 + r < M) v = A[(size_t)(row0 + r) * K + k0 + c];
            As[c][r] = v;
        }
        #pragma unroll
        for (int i = 0; i < 4; ++i) {
            int idx = t + i * 256;          // 16x64 B tile
            int r = idx >> 6, c = idx & 63;
            Bs[r][c] = B[(size_t)(k0 + r) * N + col0 + c];
        }
        __syncthreads();
        #pragma unroll
        for (int kk = 0; kk < 16; ++kk) {
            float a[4], b[4];
            #pragma unroll
            for (int i = 0; i < 4; ++i) a[i] = As[kk][ty * 4 + i];
            #pragma unroll
            for (int j = 0; j < 4; ++j) b[j] = Bs[kk][tx * 4 + j];
            #pragma unroll
            for (int i = 0; i < 4; ++i)
                #pragma unroll
                for (int j = 0; j < 4; ++j)
                    acc[i][j] = fmaf(a[i], b[j], acc[i][j]);
        }
        __syncthreads();
    }
    #pragma unroll
    for (int i = 0; i < 4; ++i) {
        int r = row0 + ty * 4 + i;
        if (r < M) {
            #pragma unroll
            for (int j = 0; j < 4; ++j) {
                int c = col0 + tx * 4 + j;
                C[(size_t)r * N + c] = acc[i][j] + bias[c];
            }
        }
    }
}

// ---------------- edge pass A: logits + segment max -----------------------
// one wave (64 lanes) per edge; lane = channel (C==64)
template <int H>
__global__ __launch_bounds__(256) void edge_logits_kernel(
    const int* __restrict__ ei, int E, int Etot,
    const float* __restrict__ xl, const float* __restrict__ xr,
    const float* __restrict__ att,
    float* __restrict__ logits, float* __restrict__ seg_max)
{
    int wave = blockIdx.x * (blockDim.x >> 6) + (threadIdx.x >> 6);
    int lane = threadIdx.x & 63;
    if (wave >= Etot) return;
    int s, d;
    if (wave < E) { s = ei[wave]; d = ei[E + wave]; }
    else          { s = wave - E; d = s; }
    const float* pl = xl + (size_t)s * (H * 64);
    const float* pr = xr + (size_t)d * (H * 64);
    #pragma unroll
    for (int h = 0; h < H; ++h) {
        float v = pl[h * 64 + lane] + pr[h * 64 + lane];
        v = v > 0.f ? v : 0.2f * v;          // leaky_relu, slope 0.2
        float p = v * att[h * 64 + lane];
        #pragma unroll
        for (int off = 32; off > 0; off >>= 1) p += __shfl_xor(p, off);
        if (lane == 0) {
            logits[(size_t)wave * H + h] = p;
            atomicMaxFloat(&seg_max[d * H + h], p);
        }
    }
}

// ---------------- edge pass B: exp + denom --------------------------------
template <int H>
__global__ void edge_exp_kernel(
    const int* __restrict__ ei, int E, int Etot,
    float* __restrict__ logits /* in: logit, out: ex */,
    const float* __restrict__ seg_max, float* __restrict__ denom)
{
    int i = blockIdx.x * blockDim.x + threadIdx.x;
    if (i >= Etot * H) return;
    int e = i / H;
    int h = i - e * H;
    int d = (e < E) ? ei[E + e] : (e - E);
    float ex = expf(logits[i] - seg_max[d * H + h]);
    logits[i] = ex;
    atomicAdd(&denom[d * H + h], ex);
}

// ---------------- edge pass C: weighted scatter-add -----------------------
template <int H>
__global__ __launch_bounds__(256) void edge_aggregate_kernel(
    const int* __restrict__ ei, int E, int Etot,
    const float* __restrict__ xl, const float* __restrict__ ex,
    float* __restrict__ agg)
{
    int wave = blockIdx.x * (blockDim.x >> 6) + (threadIdx.x >> 6);
    int lane = threadIdx.x & 63;
    if (wave >= Etot) return;
    int s, d;
    if (wave < E) { s = ei[wave]; d = ei[E + wave]; }
    else          { s = wave - E; d = s; }
    const float* pl = xl + (size_t)s * (H * 64);
    float* pa = agg + (size_t)d * (H * 64);
    #pragma unroll
    for (int h = 0; h < H; ++h) {
        float w = ex[(size_t)wave * H + h];
        atomicAdd(&pa[h * 64 + lane], w * pl[h * 64 + lane]);
    }
}

// ---------------- node epilogue: /denom + bias + relu (in place) ----------
__global__ void node_epilogue_kernel(
    const float* __restrict__ denom, const float* __restrict__ bias,
    float* __restrict__ agg, int N, int H)
{
    int i = blockIdx.x * blockDim.x + threadIdx.x;
    int HC = H * 64;
    if (i >= N * HC) return;
    int n = i / HC;
    int hc = i - n * HC;
    int h = hc >> 6;
    float v = agg[i] / denom[n * H + h] + bias[hc];
    agg[i] = v > 0.f ? v : 0.f;
}

// ---------------- pooling --------------------------------------------------
__global__ void pool_kernel(const float* __restrict__ h3,
                            const int* __restrict__ batch,
                            float* __restrict__ sums, int N)
{
    int i = blockIdx.x * blockDim.x + threadIdx.x;
    if (i >= N * 64) return;
    int n = i >> 6, c = i & 63;
    atomicAdd(&sums[batch[n] * 64 + c], h3[i]);
}

__global__ void count_kernel(const int* __restrict__ batch,
                             float* __restrict__ counts, int N)
{
    int n = blockIdx.x * blockDim.x + threadIdx.x;
    if (n < N) atomicAdd(&counts[batch[n]], 1.0f);
}

// ---------------- MLP: relu(pooled@Wm1+bm1)@Wm2+bm2 -----------------------
__global__ __launch_bounds__(64) void mlp_kernel(
    const float* __restrict__ sums, const float* __restrict__ counts,
    const float* __restrict__ Wm1, const float* __restrict__ bm1,
    const float* __restrict__ Wm2, const float* __restrict__ bm2,
    float* __restrict__ out)
{
    int g = blockIdx.x;
    int t = threadIdx.x;
    __shared__ float pooled[64];
    __shared__ float hidden[32];
    float cnt = counts[g];
    cnt = cnt > 1.f ? cnt : 1.f;
    pooled[t] = sums[g * 64 + t] / cnt;
    __syncthreads();
    if (t < 32) {
        float a = bm1[t];
        #pragma unroll
        for (int k = 0; k < 64; ++k) a = fmaf(pooled[k], Wm1[k * 32 + t], a);
        hidden[t] = a > 0.f ? a : 0.f;
    }
    __syncthreads();
    if (t < 2) {
        float a = bm2[t];
        #pragma unroll
        for (int j = 0; j < 32; ++j) a = fmaf(hidden[j], Wm2[j * 2 + t], a);
        out[g * 2 + t] = a;
    }
}

// ---------------- host-side layer driver -----------------------------------
static void run_gat_layer(const float* X, int in_dim, int H,
                          const float* Wl, const float* bl,
                          const float* Wr, const float* br,
                          const float* att, const float* bias_out,
                          const int* ei, int E, int Etot, int N,
                          float* xl, float* xr, float* logits,
                          float* seg_max, float* denom, float* h_out,
                          hipStream_t stream)
{
    const int out_dim = H * 64;
    dim3 ggrid(out_dim / 64, (N + 63) / 64);
    gemm_bias<<<ggrid, 256, 0, stream>>>(X, Wl, bl, xl, N, out_dim, in_dim);
    gemm_bias<<<ggrid, 256, 0, stream>>>(X, Wr, br, xr, N, out_dim, in_dim);

    hipMemsetAsync(seg_max, 0xFF, (size_t)N * H * sizeof(float), stream); // NaN=uint-max
    hipMemsetAsync(denom, 0, (size_t)N * H * sizeof(float), stream);
    hipMemsetAsync(h_out, 0, (size_t)N * out_dim * sizeof(float), stream);

    const int wavesPerBlock = 4;
    int blocksE = (Etot + wavesPerBlock - 1) / wavesPerBlock;
    int threadsB = (Etot * H + 255) / 256;

    if (H == 4) {
        edge_logits_kernel<4><<<blocksE, 256, 0, stream>>>(ei, E, Etot, xl, xr, att, logits, seg_max);
        edge_exp_kernel<4><<<threadsB, 256, 0, stream>>>(ei, E, Etot, logits, seg_max, denom);
        edge_aggregate_kernel<4><<<blocksE, 256, 0, stream>>>(ei, E, Etot, xl, logits, h_out);
    } else if (H == 2) {
        edge_logits_kernel<2><<<blocksE, 256, 0, stream>>>(ei, E, Etot, xl, xr, att, logits, seg_max);
        edge_exp_kernel<2><<<threadsB, 256, 0, stream>>>(ei, E, Etot, logits, seg_max, denom);
        edge_aggregate_kernel<2><<<blocksE, 256, 0, stream>>>(ei, E, Etot, xl, logits, h_out);
    } else {
        edge_logits_kernel<1><<<blocksE, 256, 0, stream>>>(ei, E, Etot, xl, xr, att, logits, seg_max);
        edge_exp_kernel<1><<<threadsB, 256, 0, stream>>>(ei, E, Etot, logits, seg_max, denom);
        edge_aggregate_kernel<1><<<blocksE, 256, 0, stream>>>(ei, E, Etot, xl, logits, h_out);
    }
    node_epilogue_kernel<<<((size_t)N * out_dim + 255) / 256, 256, 0, stream>>>(
        denom, bias_out, h_out, N, H);
}

extern "C" void kernel_launch(void* const* d_in, const int* in_sizes, int n_in,
                              void* d_out, int out_size, void* d_ws, size_t ws_size,
                              hipStream_t stream)
{
    const float* x    = (const float*)d_in[0];
    const int*   ei   = (const int*)d_in[1];
    const int*   batch= (const int*)d_in[2];
    const float* Wl1 = (const float*)d_in[3];
    const float* bl1 = (const float*)d_in[4];
    const float* Wr1 = (const float*)d_in[5];
    const float* br1 = (const float*)d_in[6];
    const float* att1= (const float*)d_in[7];
    const float* b1  = (const float*)d_in[8];
    const float* Wl2 = (const float*)d_in[9];
    const float* bl2 = (const float*)d_in[10];
    const float* Wr2 = (const float*)d_in[11];
    const float* br2 = (const float*)d_in[12];
    const float* att2= (const float*)d_in[13];
    const float* b2  = (const float*)d_in[14];
    const float* Wl3 = (const float*)d_in[15];
    const float* bl3 = (const float*)d_in[16];
    const float* Wr3 = (const float*)d_in[17];
    const float* br3 = (const float*)d_in[18];
    const float* att3= (const float*)d_in[19];
    const float* b3  = (const float*)d_in[20];
    const float* Wm1 = (const float*)d_in[21];
    const float* bm1 = (const float*)d_in[22];
    const float* Wm2 = (const float*)d_in[23];
    const float* bm2 = (const float*)d_in[24];

    const int N    = in_sizes[2];          // 50000
    const int E    = in_sizes[1] / 2;      // 800000
    const int Etot = E + N;                // + self loops
    const int in_dim = in_sizes[0] / N;    // 128

    // workspace layout (floats)
    float* ws = (float*)d_ws;
    size_t o = 0;
    float* xl      = ws + o; o += (size_t)N * 256;
    float* xr      = ws + o; o += (size_t)N * 256;
    float* hC      = ws + o; o += (size_t)N * 256;   // h1, later h3
    float* hD      = ws + o; o += (size_t)N * 128;   // h2
    float* logits  = ws + o; o += (size_t)Etot * 4;
    float* seg_max = ws + o; o += (size_t)N * 4;
    float* denom   = ws + o; o += (size_t)N * 4;
    float* sums    = ws + o; o += 64 * 64;
    float* counts  = ws + o; o += 64;
    (void)ws_size; (void)n_in; (void)out_size;

    // layer 1: in=128, H=4 -> hC [N,256]
    run_gat_layer(x, in_dim, 4, Wl1, bl1, Wr1, br1, att1, b1,
                  ei, E, Etot, N, xl, xr, logits, seg_max, denom, hC, stream);
    // layer 2: in=256, H=2 -> hD [N,128]
    run_gat_layer(hC, 256, 2, Wl2, bl2, Wr2, br2, att2, b2,
                  ei, E, Etot, N, xl, xr, logits, seg_max, denom, hD, stream);
    // layer 3: in=128, H=1 -> hC [N,64]
    run_gat_layer(hD, 128, 1, Wl3, bl3, Wr3, br3, att3, b3,
                  ei, E, Etot, N, xl, xr, logits, seg_max, denom, hC, stream);

    // global mean pool + MLP
    hipMemsetAsync(sums, 0, 64 * 64 * sizeof(float), stream);
    hipMemsetAsync(counts, 0, 64 * sizeof(float), stream);
    pool_kernel<<<((size_t)N * 64 + 255) / 256, 256, 0, stream>>>(hC, batch, sums, N);
    count_kernel<<<(N + 255) / 256, 256, 0, stream>>>(batch, counts, N);
    mlp_kernel<<<64, 64, 0, stream>>>(sums, counts, Wm1, bm1, Wm2, bm2, (float*)d_out);
}

// Round 2
// 1092.917 us; speedup vs baseline: 2.6175x; 2.6175x over previous
//
#include <hip/hip_runtime.h>

// GATv2 GNN classifier, fp32.
// R2: CSR (dst-sorted) built once per launch; per layer: 2 GEMMs + ONE fused
// edge kernel (wave per (dst,head), online softmax in registers, no f32
// atomics). Segmented pooling (batch sorted) + tiny MLP.

// ---------------- GEMM: C[M,N] = A[M,K] * B[K,N] + bias[N] ----------------
// 64x64 tile, 256 threads, 4x4 microtile, BK=16, float4 LDS reads.
__global__ __launch_bounds__(256) void gemm_bias(
    const float* __restrict__ A, const float* __restrict__ B,
    const float* __restrict__ bias, float* __restrict__ C,
    int M, int N, int K)
{
    __shared__ float As[16][68];   // 68 keeps 16B alignment for float4 reads
    __shared__ float Bs[16][68];
    const int row0 = blockIdx.y * 64;
    const int col0 = blockIdx.x * 64;
    const int t  = threadIdx.x;
    const int tx = t & 15;
    const int ty = t >> 4;
    float acc[4][4] = {};

    for (int k0 = 0; k0 < K; k0 += 16) {
        #pragma unroll
        for (int i = 0; i < 4; ++i) {
            int idx = t + i * 256;          // 64x16 A tile
            int r = idx >> 4, c = idx & 15;
            float v = 0.f;
            if (row0 + r < M) v = A[(size_t)(row0 + r) * K + k0 + c];
            As[c][r] = v;
        }
        #pragma unroll
        for (int i = 0; i < 4; ++i) {
            int idx = t + i * 256;          // 16x64 B tile
            int r = idx >> 6, c = idx & 63;
            Bs[r][c] = B[(size_t)(k0 + r) * N + col0 + c];
        }
        __syncthreads();
        #pragma unroll
        for (int kk = 0; kk < 16; ++kk) {
            float4 a4 = *reinterpret_cast<const float4*>(&As[kk][ty * 4]);
            float4 b4 = *reinterpret_cast<const float4*>(&Bs[kk][tx * 4]);
            float a[4] = {a4.x, a4.y, a4.z, a4.w};
            float b[4] = {b4.x, b4.y, b4.z, b4.w};
            #pragma unroll
            for (int i = 0; i < 4; ++i)
                #pragma unroll
                for (int j = 0; j < 4; ++j)
                    acc[i][j] = fmaf(a[i], b[j], acc[i][j]);
        }
        __syncthreads();
    }
    #pragma unroll
    for (int i = 0; i < 4; ++i) {
        int r = row0 + ty * 4 + i;
        if (r < M) {
            #pragma unroll
            for (int j = 0; j < 4; ++j) {
                int c = col0 + tx * 4 + j;
                C[(size_t)r * N + c] = acc[i][j] + bias[c];
            }
        }
    }
}

// ---------------- CSR build ------------------------------------------------
__global__ void hist_kernel(const int* __restrict__ ei, int E, int Etot,
                            int* __restrict__ deg)
{
    int i = blockIdx.x * blockDim.x + threadIdx.x;
    if (i >= Etot) return;
    int d = (i < E) ? ei[E + i] : (i - E);
    atomicAdd(&deg[d], 1);
}

// single block, 1024 threads: exclusive scan deg[0..N) -> rowptr, cursor
__global__ __launch_bounds__(1024) void scan_kernel(
    const int* __restrict__ deg, int* __restrict__ rowptr,
    int* __restrict__ cursor, int N)
{
    __shared__ int part[1024];
    const int t = threadIdx.x;
    const int chunk = (N + 1023) / 1024;
    const int lo = t * chunk;
    const int hi = (lo + chunk < N) ? lo + chunk : N;
    int s = 0;
    for (int i = lo; i < hi; ++i) s += deg[i];
    part[t] = s;
    __syncthreads();
    for (int off = 1; off < 1024; off <<= 1) {
        int v = (t >= off) ? part[t - off] : 0;
        __syncthreads();
        part[t] += v;
        __syncthreads();
    }
    int base = (t == 0) ? 0 : part[t - 1];
    for (int i = lo; i < hi; ++i) {
        rowptr[i] = base;
        cursor[i] = base;
        base += deg[i];
    }
    if (t == 1023) rowptr[N] = part[1023];
}

__global__ void scatter_kernel(const int* __restrict__ ei, int E, int Etot,
                               int* __restrict__ cursor,
                               int* __restrict__ ssrc)
{
    int i = blockIdx.x * blockDim.x + threadIdx.x;
    if (i >= Etot) return;
    int d, s;
    if (i < E) { s = ei[i]; d = ei[E + i]; }
    else       { s = i - E; d = s; }
    int pos = atomicAdd(&cursor[d], 1);
    ssrc[pos] = s;
}

// ---------------- fused edge kernel ---------------------------------------
// one wave per (dst, head); lane = channel. Online softmax in registers.
template <int H>
__global__ __launch_bounds__(256) void gat_fused(
    const int* __restrict__ rowptr, const int* __restrict__ ssrc,
    const float* __restrict__ xl, const float* __restrict__ xr,
    const float* __restrict__ att, const float* __restrict__ bias,
    float* __restrict__ out, int N)
{
    const int wid = blockIdx.x * 4 + (threadIdx.x >> 6);
    const int lane = threadIdx.x & 63;
    if (wid >= N * H) return;
    const int d = wid / H;
    const int h = wid - d * H;
    const int HC = H * 64;

    const float xrv  = xr[(size_t)d * HC + h * 64 + lane];
    const float attv = att[h * 64 + lane];
    const int begin = rowptr[d];
    const int end   = rowptr[d + 1];

    float M = -3.0e38f, S = 0.f;
    float acc = 0.f;

    int s = ssrc[begin];
    float xlv = xl[(size_t)s * HC + h * 64 + lane];
    for (int e = begin; e < end; ++e) {
        float cur = xlv;
        if (e + 1 < end) {                      // prefetch next gather
            int sn = ssrc[e + 1];
            xlv = xl[(size_t)sn * HC + h * 64 + lane];
        }
        float v = cur + xrv;
        v = v > 0.f ? v : 0.2f * v;             // leaky_relu 0.2
        float p = v * attv;
        #pragma unroll
        for (int off = 32; off; off >>= 1) p += __shfl_xor(p, off);
        float newM = fmaxf(M, p);
        float scale = __expf(M - newM);
        float w = __expf(p - newM);
        S = S * scale + w;
        acc = fmaf(acc, scale, w * cur);
        M = newM;
    }
    float val = acc / S + bias[h * 64 + lane];
    out[(size_t)wid * 64 + lane] = val > 0.f ? val : 0.f;
}

// ---------------- segmented pool (batch sorted) + counts ------------------
__global__ __launch_bounds__(256) void pool_kernel2(
    const float* __restrict__ h3, const int* __restrict__ batch,
    float* __restrict__ sums, float* __restrict__ counts, int N)
{
    const int wave = blockIdx.x * 4 + (threadIdx.x >> 6);
    const int lane = threadIdx.x & 63;
    const int n0 = wave * 64;
    if (n0 >= N) return;
    const int n1 = (n0 + 64 < N) ? n0 + 64 : N;
    float s = 0.f, cnt = 0.f;
    int g = batch[n0];
    for (int n = n0; n < n1; ++n) {
        int gn = batch[n];
        if (gn != g) {
            atomicAdd(&sums[g * 64 + lane], s);
            if (lane == 0) atomicAdd(&counts[g], cnt);
            s = 0.f; cnt = 0.f; g = gn;
        }
        s += h3[(size_t)n * 64 + lane];
        cnt += 1.f;
    }
    atomicAdd(&sums[g * 64 + lane], s);
    if (lane == 0) atomicAdd(&counts[g], cnt);
}

// ---------------- MLP ------------------------------------------------------
__global__ __launch_bounds__(64) void mlp_kernel(
    const float* __restrict__ sums, const float* __restrict__ counts,
    const float* __restrict__ Wm1, const float* __restrict__ bm1,
    const float* __restrict__ Wm2, const float* __restrict__ bm2,
    float* __restrict__ out)
{
    int g = blockIdx.x;
    int t = threadIdx.x;
    __shared__ float pooled[64];
    __shared__ float hidden[32];
    float cnt = counts[g];
    cnt = cnt > 1.f ? cnt : 1.f;
    pooled[t] = sums[g * 64 + t] / cnt;
    __syncthreads();
    if (t < 32) {
        float a = bm1[t];
        #pragma unroll
        for (int k = 0; k < 64; ++k) a = fmaf(pooled[k], Wm1[k * 32 + t], a);
        hidden[t] = a > 0.f ? a : 0.f;
    }
    __syncthreads();
    if (t < 2) {
        float a = bm2[t];
        #pragma unroll
        for (int j = 0; j < 32; ++j) a = fmaf(hidden[j], Wm2[j * 2 + t], a);
        out[g * 2 + t] = a;
    }
}

// ---------------- layer driver ---------------------------------------------
static void run_gat_layer(const float* X, int in_dim, int H,
                          const float* Wl, const float* bl,
                          const float* Wr, const float* br,
                          const float* att, const float* bias_out,
                          const int* rowptr, const int* ssrc, int N,
                          float* xl, float* xr, float* h_out,
                          hipStream_t stream)
{
    const int out_dim = H * 64;
    dim3 ggrid(out_dim / 64, (N + 63) / 64);
    gemm_bias<<<ggrid, 256, 0, stream>>>(X, Wl, bl, xl, N, out_dim, in_dim);
    gemm_bias<<<ggrid, 256, 0, stream>>>(X, Wr, br, xr, N, out_dim, in_dim);

    int waves = N * H;
    int blocks = (waves + 3) / 4;
    if (H == 4)
        gat_fused<4><<<blocks, 256, 0, stream>>>(rowptr, ssrc, xl, xr, att, bias_out, h_out, N);
    else if (H == 2)
        gat_fused<2><<<blocks, 256, 0, stream>>>(rowptr, ssrc, xl, xr, att, bias_out, h_out, N);
    else
        gat_fused<1><<<blocks, 256, 0, stream>>>(rowptr, ssrc, xl, xr, att, bias_out, h_out, N);
}

extern "C" void kernel_launch(void* const* d_in, const int* in_sizes, int n_in,
                              void* d_out, int out_size, void* d_ws, size_t ws_size,
                              hipStream_t stream)
{
    const float* x    = (const float*)d_in[0];
    const int*   ei   = (const int*)d_in[1];
    const int*   batch= (const int*)d_in[2];
    const float* Wl1 = (const float*)d_in[3];
    const float* bl1 = (const float*)d_in[4];
    const float* Wr1 = (const float*)d_in[5];
    const float* br1 = (const float*)d_in[6];
    const float* att1= (const float*)d_in[7];
    const float* b1  = (const float*)d_in[8];
    const float* Wl2 = (const float*)d_in[9];
    const float* bl2 = (const float*)d_in[10];
    const float* Wr2 = (const float*)d_in[11];
    const float* br2 = (const float*)d_in[12];
    const float* att2= (const float*)d_in[13];
    const float* b2  = (const float*)d_in[14];
    const float* Wl3 = (const float*)d_in[15];
    const float* bl3 = (const float*)d_in[16];
    const float* Wr3 = (const float*)d_in[17];
    const float* br3 = (const float*)d_in[18];
    const float* att3= (const float*)d_in[19];
    const float* b3  = (const float*)d_in[20];
    const float* Wm1 = (const float*)d_in[21];
    const float* bm1 = (const float*)d_in[22];
    const float* Wm2 = (const float*)d_in[23];
    const float* bm2 = (const float*)d_in[24];

    const int N    = in_sizes[2];          // 50000
    const int E    = in_sizes[1] / 2;      // 800000
    const int Etot = E + N;                // + self loops
    const int in_dim = in_sizes[0] / N;    // 128

    // workspace layout
    char* wsb = (char*)d_ws;
    size_t o = 0;
    auto alloc = [&](size_t bytes) { char* p = wsb + o; o += (bytes + 255) & ~(size_t)255; return p; };
    float* xl      = (float*)alloc((size_t)N * 256 * 4);
    float* xr      = (float*)alloc((size_t)N * 256 * 4);
    float* hC      = (float*)alloc((size_t)N * 256 * 4);   // h1, later h3
    float* hD      = (float*)alloc((size_t)N * 128 * 4);   // h2
    int*   deg     = (int*)alloc((size_t)(N) * 4);
    int*   rowptr  = (int*)alloc((size_t)(N + 1) * 4);
    int*   cursor  = (int*)alloc((size_t)(N) * 4);
    int*   ssrc    = (int*)alloc((size_t)Etot * 4);
    float* sums    = (float*)alloc(64 * 64 * 4);
    float* counts  = (float*)alloc(64 * 4);
    (void)ws_size; (void)n_in; (void)out_size;

    // ---- CSR build (once; shared by all 3 layers) ----
    hipMemsetAsync(deg, 0, (size_t)N * 4, stream);
    hist_kernel<<<(Etot + 255) / 256, 256, 0, stream>>>(ei, E, Etot, deg);
    scan_kernel<<<1, 1024, 0, stream>>>(deg, rowptr, cursor, N);
    scatter_kernel<<<(Etot + 255) / 256, 256, 0, stream>>>(ei, E, Etot, cursor, ssrc);

    // ---- layers ----
    run_gat_layer(x, in_dim, 4, Wl1, bl1, Wr1, br1, att1, b1,
                  rowptr, ssrc, N, xl, xr, hC, stream);
    run_gat_layer(hC, 256, 2, Wl2, bl2, Wr2, br2, att2, b2,
                  rowptr, ssrc, N, xl, xr, hD, stream);
    run_gat_layer(hD, 128, 1, Wl3, bl3, Wr3, br3, att3, b3,
                  rowptr, ssrc, N, xl, xr, hC, stream);

    // ---- pool + MLP ----
    hipMemsetAsync(sums, 0, 64 * 64 * 4, stream);
    hipMemsetAsync(counts, 0, 64 * 4, stream);
    {
        int waves = (N + 63) / 64;
        pool_kernel2<<<(waves + 3) / 4, 256, 0, stream>>>(hC, batch, sums, counts, N);
    }
    mlp_kernel<<<64, 64, 0, stream>>>(sums, counts, Wm1, bm1, Wm2, bm2, (float*)d_out);
}

// Round 3
// 956.098 us; speedup vs baseline: 2.9920x; 1.1431x over previous
//
#include <hip/hip_runtime.h>

// GATv2 GNN classifier.
// R3: (a) edge kernel restructured to 4-lane groups (2-shfl reduce, 16 ch/lane),
//     degree-sorted dst processing to kill intra-wave divergence;
//     (b) GEMMs via bf16 MFMA 16x16x32 (fp32 accum), XOR-swizzled LDS;
//     activations handed to next layer as bf16 directly.

typedef __attribute__((ext_vector_type(8))) short bf16x8;
typedef __attribute__((ext_vector_type(4))) float f32x4;

__device__ inline unsigned short f2bf(float f) {
    unsigned u = __float_as_uint(f);
    unsigned r = (u + 0x7fff + ((u >> 16) & 1)) >> 16;   // RNE
    return (unsigned short)r;
}

// ---------------- fp32 -> bf16 elementwise convert ------------------------
__global__ void cvt_kernel(const float* __restrict__ in,
                           unsigned short* __restrict__ out, int n)
{
    int i = (blockIdx.x * blockDim.x + threadIdx.x) * 4;
    if (i >= n) return;
    float4 v = *reinterpret_cast<const float4*>(in + i);
    ushort4 o;
    o.x = f2bf(v.x); o.y = f2bf(v.y); o.z = f2bf(v.z); o.w = f2bf(v.w);
    *reinterpret_cast<ushort4*>(out + i) = o;
}

// ---------------- W [K][No] fp32 -> Wt [No][K] bf16 -----------------------
__global__ void cvt_wt_kernel(const float* __restrict__ W,
                              unsigned short* __restrict__ Wt, int K, int No)
{
    int idx = blockIdx.x * blockDim.x + threadIdx.x;
    if (idx >= K * No) return;
    int n = idx / K, k = idx - n * K;
    Wt[idx] = f2bf(W[(size_t)k * No + n]);
}

// ---------------- MFMA GEMM: C[M,No] = A[M,K](bf16) * Wt^T + bias ---------
// BM=128, BN=64, BK=64; 256 threads (4 waves, 2x2); z picks (W,bias,C) pair.
__global__ __launch_bounds__(256) void gemm_mfma(
    const unsigned short* __restrict__ A,     // [M][K] bf16
    const unsigned short* __restrict__ W0, const unsigned short* __restrict__ W1,
    const float* __restrict__ bias0, const float* __restrict__ bias1,
    float* __restrict__ C0, float* __restrict__ C1,
    int M, int No, int K)
{
    const unsigned short* Wt = blockIdx.z ? W1 : W0;  // [No][K] bf16
    const float* bias = blockIdx.z ? bias1 : bias0;
    float* C = blockIdx.z ? C1 : C0;

    __shared__ __align__(16) char smem[128 * 64 * 2 + 64 * 64 * 2]; // A 16K + B 8K
    char* As = smem;
    char* Bs = smem + 16384;

    const int t = threadIdx.x;
    const int lane = t & 63;
    const int wid = t >> 6;
    const int wm = wid >> 1, wn = wid & 1;
    const int row0 = blockIdx.x * 128;
    const int col0 = blockIdx.y * 64;
    const int nk = K >> 6;

    f32x4 acc[4][2];
    #pragma unroll
    for (int i = 0; i < 4; ++i)
        #pragma unroll
        for (int j = 0; j < 2; ++j)
            acc[i][j] = (f32x4){0.f, 0.f, 0.f, 0.f};

    uint4 stA[4]; uint4 stB[2];
    // A staging: thread covers 4 16B chunks; chunk c16 -> row=c16/8, j=c16%8
    // B staging: 2 chunks.
    {
        #pragma unroll
        for (int i = 0; i < 4; ++i) {
            int c16 = t * 4 + i; int r = c16 >> 3, j = c16 & 7;
            int gr = row0 + r; if (gr > M - 1) gr = M - 1;
            stA[i] = *reinterpret_cast<const uint4*>(A + (size_t)gr * K + j * 8);
        }
        #pragma unroll
        for (int i = 0; i < 2; ++i) {
            int c16 = t * 2 + i; int n = c16 >> 3, j = c16 & 7;
            stB[i] = *reinterpret_cast<const uint4*>(Wt + (size_t)(col0 + n) * K + j * 8);
        }
    }

    for (int kt = 0; kt < nk; ++kt) {
        // swizzled LDS write: chunk j of row r lands at (j ^ (r&7))*16
        #pragma unroll
        for (int i = 0; i < 4; ++i) {
            int c16 = t * 4 + i; int r = c16 >> 3, j = c16 & 7;
            *reinterpret_cast<uint4*>(As + r * 128 + ((j ^ (r & 7)) << 4)) = stA[i];
        }
        #pragma unroll
        for (int i = 0; i < 2; ++i) {
            int c16 = t * 2 + i; int n = c16 >> 3, j = c16 & 7;
            *reinterpret_cast<uint4*>(Bs + n * 128 + ((j ^ (n & 7)) << 4)) = stB[i];
        }
        __syncthreads();
        if (kt + 1 < nk) {
            int ko = (kt + 1) * 64;
            #pragma unroll
            for (int i = 0; i < 4; ++i) {
                int c16 = t * 4 + i; int r = c16 >> 3, j = c16 & 7;
                int gr = row0 + r; if (gr > M - 1) gr = M - 1;
                stA[i] = *reinterpret_cast<const uint4*>(A + (size_t)gr * K + ko + j * 8);
            }
            #pragma unroll
            for (int i = 0; i < 2; ++i) {
                int c16 = t * 2 + i; int n = c16 >> 3, j = c16 & 7;
                stB[i] = *reinterpret_cast<const uint4*>(Wt + (size_t)(col0 + n) * K + ko + j * 8);
            }
        }
        #pragma unroll
        for (int kk = 0; kk < 2; ++kk) {
            bf16x8 a[4], b[2];
            const int kb2 = (kk * 32 + (lane >> 4) * 8) * 2;   // byte offset in row
            #pragma unroll
            for (int i = 0; i < 4; ++i) {
                int r = wm * 64 + i * 16 + (lane & 15);
                a[i] = *reinterpret_cast<const bf16x8*>(As + r * 128 + (kb2 ^ ((r & 7) << 4)));
            }
            #pragma unroll
            for (int j = 0; j < 2; ++j) {
                int n = wn * 32 + j * 16 + (lane & 15);
                b[j] = *reinterpret_cast<const bf16x8*>(Bs + n * 128 + (kb2 ^ ((n & 7) << 4)));
            }
            #pragma unroll
            for (int i = 0; i < 4; ++i)
                #pragma unroll
                for (int j = 0; j < 2; ++j)
                    acc[i][j] = __builtin_amdgcn_mfma_f32_16x16x32_bf16(a[i], b[j], acc[i][j], 0, 0, 0);
        }
        __syncthreads();
    }

    // epilogue: C/D layout col=lane&15, row=(lane>>4)*4+q
    #pragma unroll
    for (int j = 0; j < 2; ++j) {
        int c = col0 + wn * 32 + j * 16 + (lane & 15);
        float bb = bias[c];
        #pragma unroll
        for (int i = 0; i < 4; ++i) {
            #pragma unroll
            for (int q = 0; q < 4; ++q) {
                int r = row0 + wm * 64 + i * 16 + (lane >> 4) * 4 + q;
                if (r < M) C[(size_t)r * No + c] = acc[i][j][q] + bb;
            }
        }
    }
}

// ---------------- CSR build ------------------------------------------------
__global__ void hist_kernel(const int* __restrict__ ei, int E, int Etot,
                            int* __restrict__ deg)
{
    int i = blockIdx.x * blockDim.x + threadIdx.x;
    if (i >= Etot) return;
    int d = (i < E) ? ei[E + i] : (i - E);
    atomicAdd(&deg[d], 1);
}

__global__ __launch_bounds__(1024) void scan_kernel(
    const int* __restrict__ deg, int* __restrict__ rowptr,
    int* __restrict__ cursor, int N)
{
    __shared__ int part[1024];
    const int t = threadIdx.x;
    const int chunk = (N + 1023) / 1024;
    const int lo = t * chunk;
    const int hi = (lo + chunk < N) ? lo + chunk : N;
    int s = 0;
    for (int i = lo; i < hi; ++i) s += deg[i];
    part[t] = s;
    __syncthreads();
    for (int off = 1; off < 1024; off <<= 1) {
        int v = (t >= off) ? part[t - off] : 0;
        __syncthreads();
        part[t] += v;
        __syncthreads();
    }
    int base = (t == 0) ? 0 : part[t - 1];
    for (int i = lo; i < hi; ++i) {
        rowptr[i] = base;
        cursor[i] = base;
        base += deg[i];
    }
    if (t == 1023) rowptr[N] = part[1023];
}

__global__ void scatter_kernel(const int* __restrict__ ei, int E, int Etot,
                               int* __restrict__ cursor, int* __restrict__ ssrc)
{
    int i = blockIdx.x * blockDim.x + threadIdx.x;
    if (i >= Etot) return;
    int d, s;
    if (i < E) { s = ei[i]; d = ei[E + i]; }
    else       { s = i - E; d = s; }
    int pos = atomicAdd(&cursor[d], 1);
    ssrc[pos] = s;
}

// ---------------- degree-sort of dsts (256-bin counting sort) -------------
__global__ void dhist_kernel(const int* __restrict__ rowptr, int* __restrict__ dh, int N)
{
    int d = blockIdx.x * blockDim.x + threadIdx.x;
    if (d >= N) return;
    int deg = rowptr[d + 1] - rowptr[d];
    atomicAdd(&dh[deg > 255 ? 255 : deg], 1);
}

__global__ __launch_bounds__(256) void dscan_kernel(const int* __restrict__ dh,
                                                    int* __restrict__ dcur)
{
    __shared__ int tmp[256];
    int t = threadIdx.x;
    tmp[t] = dh[t];
    __syncthreads();
    for (int off = 1; off < 256; off <<= 1) {
        int v = (t >= off) ? tmp[t - off] : 0;
        __syncthreads();
        tmp[t] += v;
        __syncthreads();
    }
    dcur[t] = (t == 0) ? 0 : tmp[t - 1];
}

__global__ void dscatter_kernel(const int* __restrict__ rowptr, int* __restrict__ dcur,
                                int* __restrict__ dperm, int N)
{
    int d = blockIdx.x * blockDim.x + threadIdx.x;
    if (d >= N) return;
    int deg = rowptr[d + 1] - rowptr[d];
    int pos = atomicAdd(&dcur[deg > 255 ? 255 : deg], 1);
    dperm[pos] = d;
}

// ---------------- fused edge kernel: 4-lane group per (dst, head) ---------
template <int H, bool OUT_F32, bool OUT_BF16>
__global__ __launch_bounds__(256) void gat_fused4(
    const int* __restrict__ rowptr, const int* __restrict__ ssrc,
    const int* __restrict__ dperm,
    const float* __restrict__ xl, const float* __restrict__ xr,
    const float* __restrict__ att, const float* __restrict__ bias,
    float* __restrict__ outf, unsigned short* __restrict__ outb, int N)
{
    const int gid = blockIdx.x * 64 + (threadIdx.x >> 2);
    const int sub = threadIdx.x & 3;
    if (gid >= N * H) return;
    const int di = gid / H;
    const int h  = gid - di * H;
    const int d  = dperm[di];
    const int HC = H * 64;
    const int co = h * 64 + sub * 16;     // channel offset within HC

    float xrv[16], attv[16], acc[16];
    {
        const float* pr = xr + (size_t)d * HC + co;
        const float* pa = att + co;
        #pragma unroll
        for (int k = 0; k < 16; k += 4) {
            float4 v = *reinterpret_cast<const float4*>(pr + k);
            xrv[k] = v.x; xrv[k+1] = v.y; xrv[k+2] = v.z; xrv[k+3] = v.w;
            float4 w = *reinterpret_cast<const float4*>(pa + k);
            attv[k] = w.x; attv[k+1] = w.y; attv[k+2] = w.z; attv[k+3] = w.w;
        }
    }
    #pragma unroll
    for (int k = 0; k < 16; ++k) acc[k] = 0.f;
    float M = -3.0e38f, S = 0.f;

    const int begin = rowptr[d], end = rowptr[d + 1];
    int s = ssrc[begin];
    float cur[16];
    {
        const float* pl = xl + (size_t)s * HC + co;
        #pragma unroll
        for (int k = 0; k < 16; k += 4) {
            float4 v = *reinterpret_cast<const float4*>(pl + k);
            cur[k] = v.x; cur[k+1] = v.y; cur[k+2] = v.z; cur[k+3] = v.w;
        }
    }
    for (int e = begin; e < end; ++e) {
        float nxt[16];
        const bool more = (e + 1 < end);
        if (more) {
            int sn = ssrc[e + 1];
            const float* pl = xl + (size_t)sn * HC + co;
            #pragma unroll
            for (int k = 0; k < 16; k += 4) {
                float4 v = *reinterpret_cast<const float4*>(pl + k);
                nxt[k] = v.x; nxt[k+1] = v.y; nxt[k+2] = v.z; nxt[k+3] = v.w;
            }
        }
        float p = 0.f;
        #pragma unroll
        for (int k = 0; k < 16; ++k) {
            float v = cur[k] + xrv[k];
            v = fmaxf(v, 0.2f * v);           // leaky_relu 0.2
            p = fmaf(v, attv[k], p);
        }
        p += __shfl_xor(p, 1);
        p += __shfl_xor(p, 2);
        float nM = fmaxf(M, p);
        float scale = __expf(M - nM);
        float w = __expf(p - nM);
        S = fmaf(S, scale, w);
        #pragma unroll
        for (int k = 0; k < 16; ++k) acc[k] = fmaf(acc[k], scale, w * cur[k]);
        M = nM;
        if (more) {
            #pragma unroll
            for (int k = 0; k < 16; ++k) cur[k] = nxt[k];
        }
    }
    float inv = 1.f / S;
    const float* pb = bias + co;
    #pragma unroll
    for (int k = 0; k < 16; ++k) {
        float val = fmaf(acc[k], inv, pb[k]);
        acc[k] = val > 0.f ? val : 0.f;
    }
    size_t ob = (size_t)d * HC + co;
    if (OUT_F32) {
        #pragma unroll
        for (int k = 0; k < 16; k += 4) {
            float4 v = {acc[k], acc[k+1], acc[k+2], acc[k+3]};
            *reinterpret_cast<float4*>(outf + ob + k) = v;
        }
    }
    if (OUT_BF16) {
        unsigned pk[8];
        #pragma unroll
        for (int k = 0; k < 8; ++k)
            pk[k] = (unsigned)f2bf(acc[2*k]) | ((unsigned)f2bf(acc[2*k+1]) << 16);
        uint4 lo = {pk[0], pk[1], pk[2], pk[3]};
        uint4 hi = {pk[4], pk[5], pk[6], pk[7]};
        *reinterpret_cast<uint4*>(outb + ob) = lo;
        *reinterpret_cast<uint4*>(outb + ob + 8) = hi;
    }
}

// ---------------- segmented pool (batch sorted) + counts ------------------
__global__ __launch_bounds__(256) void pool_kernel2(
    const float* __restrict__ h3, const int* __restrict__ batch,
    float* __restrict__ sums, float* __restrict__ counts, int N)
{
    const int wave = blockIdx.x * 4 + (threadIdx.x >> 6);
    const int lane = threadIdx.x & 63;
    const int n0 = wave * 64;
    if (n0 >= N) return;
    const int n1 = (n0 + 64 < N) ? n0 + 64 : N;
    float s = 0.f, cnt = 0.f;
    int g = batch[n0];
    for (int n = n0; n < n1; ++n) {
        int gn = batch[n];
        if (gn != g) {
            atomicAdd(&sums[g * 64 + lane], s);
            if (lane == 0) atomicAdd(&counts[g], cnt);
            s = 0.f; cnt = 0.f; g = gn;
        }
        s += h3[(size_t)n * 64 + lane];
        cnt += 1.f;
    }
    atomicAdd(&sums[g * 64 + lane], s);
    if (lane == 0) atomicAdd(&counts[g], cnt);
}

// ---------------- MLP ------------------------------------------------------
__global__ __launch_bounds__(64) void mlp_kernel(
    const float* __restrict__ sums, const float* __restrict__ counts,
    const float* __restrict__ Wm1, const float* __restrict__ bm1,
    const float* __restrict__ Wm2, const float* __restrict__ bm2,
    float* __restrict__ out)
{
    int g = blockIdx.x;
    int t = threadIdx.x;
    __shared__ float pooled[64];
    __shared__ float hidden[32];
    float cnt = counts[g];
    cnt = cnt > 1.f ? cnt : 1.f;
    pooled[t] = sums[g * 64 + t] / cnt;
    __syncthreads();
    if (t < 32) {
        float a = bm1[t];
        #pragma unroll
        for (int k = 0; k < 64; ++k) a = fmaf(pooled[k], Wm1[k * 32 + t], a);
        hidden[t] = a > 0.f ? a : 0.f;
    }
    __syncthreads();
    if (t < 2) {
        float a = bm2[t];
        #pragma unroll
        for (int j = 0; j < 32; ++j) a = fmaf(hidden[j], Wm2[j * 2 + t], a);
        out[g * 2 + t] = a;
    }
}

// ---------------- layer driver ---------------------------------------------
static void run_layer(const unsigned short* Xb, int K, int H,
                      const float* Wl, const float* bl,
                      const float* Wr, const float* br,
                      const float* att, const float* bias_out,
                      unsigned short* Wtl, unsigned short* Wtr,
                      const int* rowptr, const int* ssrc, const int* dperm, int N,
                      float* xl, float* xr, float* houtf, unsigned short* houtb,
                      hipStream_t stream)
{
    const int No = H * 64;
    const int nw = K * No;
    cvt_wt_kernel<<<(nw + 255) / 256, 256, 0, stream>>>(Wl, Wtl, K, No);
    cvt_wt_kernel<<<(nw + 255) / 256, 256, 0, stream>>>(Wr, Wtr, K, No);
    dim3 g((N + 127) / 128, No / 64, 2);
    gemm_mfma<<<g, 256, 0, stream>>>(Xb, Wtl, Wtr, bl, br, xl, xr, N, No, K);

    int ngroups = N * H;
    int blocks = (ngroups + 63) / 64;
    if (H == 4)
        gat_fused4<4, false, true><<<blocks, 256, 0, stream>>>(
            rowptr, ssrc, dperm, xl, xr, att, bias_out, houtf, houtb, N);
    else if (H == 2)
        gat_fused4<2, false, true><<<blocks, 256, 0, stream>>>(
            rowptr, ssrc, dperm, xl, xr, att, bias_out, houtf, houtb, N);
    else
        gat_fused4<1, true, false><<<blocks, 256, 0, stream>>>(
            rowptr, ssrc, dperm, xl, xr, att, bias_out, houtf, houtb, N);
}

extern "C" void kernel_launch(void* const* d_in, const int* in_sizes, int n_in,
                              void* d_out, int out_size, void* d_ws, size_t ws_size,
                              hipStream_t stream)
{
    const float* x    = (const float*)d_in[0];
    const int*   ei   = (const int*)d_in[1];
    const int*   batch= (const int*)d_in[2];
    const float* Wl1 = (const float*)d_in[3];
    const float* bl1 = (const float*)d_in[4];
    const float* Wr1 = (const float*)d_in[5];
    const float* br1 = (const float*)d_in[6];
    const float* att1= (const float*)d_in[7];
    const float* b1  = (const float*)d_in[8];
    const float* Wl2 = (const float*)d_in[9];
    const float* bl2 = (const float*)d_in[10];
    const float* Wr2 = (const float*)d_in[11];
    const float* br2 = (const float*)d_in[12];
    const float* att2= (const float*)d_in[13];
    const float* b2  = (const float*)d_in[14];
    const float* Wl3 = (const float*)d_in[15];
    const float* bl3 = (const float*)d_in[16];
    const float* Wr3 = (const float*)d_in[17];
    const float* br3 = (const float*)d_in[18];
    const float* att3= (const float*)d_in[19];
    const float* b3  = (const float*)d_in[20];
    const float* Wm1 = (const float*)d_in[21];
    const float* bm1 = (const float*)d_in[22];
    const float* Wm2 = (const float*)d_in[23];
    const float* bm2 = (const float*)d_in[24];

    const int N    = in_sizes[2];          // 50000
    const int E    = in_sizes[1] / 2;      // 800000
    const int Etot = E + N;                // + self loops
    const int K1   = in_sizes[0] / N;      // 128

    // workspace layout
    char* wsb = (char*)d_ws;
    size_t o = 0;
    auto alloc = [&](size_t bytes) { char* p = wsb + o; o += (bytes + 255) & ~(size_t)255; return p; };
    float*          xl    = (float*)alloc((size_t)N * 256 * 4);
    float*          xr    = (float*)alloc((size_t)N * 256 * 4);
    unsigned short* xb    = (unsigned short*)alloc((size_t)N * K1 * 2);
    unsigned short* h1b   = (unsigned short*)alloc((size_t)N * 256 * 2);
    unsigned short* h2b   = (unsigned short*)alloc((size_t)N * 128 * 2);
    float*          h3f   = (float*)alloc((size_t)N * 64 * 4);
    int*   deg    = (int*)alloc((size_t)N * 4);
    int*   rowptr = (int*)alloc((size_t)(N + 1) * 4);
    int*   cursor = (int*)alloc((size_t)N * 4);
    int*   ssrc   = (int*)alloc((size_t)Etot * 4);
    int*   dperm  = (int*)alloc((size_t)N * 4);
    int*   dh     = (int*)alloc(256 * 4);
    int*   dcur   = (int*)alloc(256 * 4);
    unsigned short* Wtl = (unsigned short*)alloc(256 * 256 * 2);
    unsigned short* Wtr = (unsigned short*)alloc(256 * 256 * 2);
    float* sums   = (float*)alloc(64 * 64 * 4);
    float* counts = (float*)alloc(64 * 4);
    (void)ws_size; (void)n_in; (void)out_size;

    // ---- CSR build + degree sort (shared by all 3 layers) ----
    hipMemsetAsync(deg, 0, (size_t)N * 4, stream);
    hipMemsetAsync(dh, 0, 256 * 4, stream);
    hist_kernel<<<(Etot + 255) / 256, 256, 0, stream>>>(ei, E, Etot, deg);
    scan_kernel<<<1, 1024, 0, stream>>>(deg, rowptr, cursor, N);
    scatter_kernel<<<(Etot + 255) / 256, 256, 0, stream>>>(ei, E, Etot, cursor, ssrc);
    dhist_kernel<<<(N + 255) / 256, 256, 0, stream>>>(rowptr, dh, N);
    dscan_kernel<<<1, 256, 0, stream>>>(dh, dcur);
    dscatter_kernel<<<(N + 255) / 256, 256, 0, stream>>>(rowptr, dcur, dperm, N);

    // ---- convert input x to bf16 ----
    cvt_kernel<<<((N * K1) / 4 + 255) / 256, 256, 0, stream>>>(x, xb, N * K1);

    // ---- layers ----
    run_layer(xb, K1, 4, Wl1, bl1, Wr1, br1, att1, b1, Wtl, Wtr,
              rowptr, ssrc, dperm, N, xl, xr, nullptr, h1b, stream);
    run_layer(h1b, 256, 2, Wl2, bl2, Wr2, br2, att2, b2, Wtl, Wtr,
              rowptr, ssrc, dperm, N, xl, xr, nullptr, h2b, stream);
    run_layer(h2b, 128, 1, Wl3, bl3, Wr3, br3, att3, b3, Wtl, Wtr,
              rowptr, ssrc, dperm, N, xl, xr, h3f, nullptr, stream);

    // ---- pool + MLP ----
    hipMemsetAsync(sums, 0, 64 * 64 * 4, stream);
    hipMemsetAsync(counts, 0, 64 * 4, stream);
    {
        int waves = (N + 63) / 64;
        pool_kernel2<<<(waves + 3) / 4, 256, 0, stream>>>(h3f, batch, sums, counts, N);
    }
    mlp_kernel<<<64, 64, 0, stream>>>(sums, counts, Wm1, bm1, Wm2, bm2, (float*)d_out);
}

// Round 4
// 686.861 us; speedup vs baseline: 4.1648x; 1.3920x over previous
//
#include <hip/hip_runtime.h>

// GATv2 GNN classifier.
// R4: contention-free degree counting-sort (per-block LDS histograms +
// offset table) replacing the 256-bin global-atomic sort (was 2x139 us).
// Rest identical to R3: bf16 MFMA GEMMs, 4-lane-group fused edge kernel.

typedef __attribute__((ext_vector_type(8))) short bf16x8;
typedef __attribute__((ext_vector_type(4))) float f32x4;

#define SORT_BLOCKS 128

__device__ inline unsigned short f2bf(float f) {
    unsigned u = __float_as_uint(f);
    unsigned r = (u + 0x7fff + ((u >> 16) & 1)) >> 16;   // RNE
    return (unsigned short)r;
}

// ---------------- fp32 -> bf16 elementwise convert ------------------------
__global__ void cvt_kernel(const float* __restrict__ in,
                           unsigned short* __restrict__ out, int n)
{
    int i = (blockIdx.x * blockDim.x + threadIdx.x) * 4;
    if (i >= n) return;
    float4 v = *reinterpret_cast<const float4*>(in + i);
    ushort4 o;
    o.x = f2bf(v.x); o.y = f2bf(v.y); o.z = f2bf(v.z); o.w = f2bf(v.w);
    *reinterpret_cast<ushort4*>(out + i) = o;
}

// ---------------- W [K][No] fp32 -> Wt [No][K] bf16 -----------------------
__global__ void cvt_wt_kernel(const float* __restrict__ W,
                              unsigned short* __restrict__ Wt, int K, int No)
{
    int idx = blockIdx.x * blockDim.x + threadIdx.x;
    if (idx >= K * No) return;
    int n = idx / K, k = idx - n * K;
    Wt[idx] = f2bf(W[(size_t)k * No + n]);
}

// ---------------- MFMA GEMM: C[M,No] = A[M,K](bf16) * Wt^T + bias ---------
__global__ __launch_bounds__(256) void gemm_mfma(
    const unsigned short* __restrict__ A,     // [M][K] bf16
    const unsigned short* __restrict__ W0, const unsigned short* __restrict__ W1,
    const float* __restrict__ bias0, const float* __restrict__ bias1,
    float* __restrict__ C0, float* __restrict__ C1,
    int M, int No, int K)
{
    const unsigned short* Wt = blockIdx.z ? W1 : W0;  // [No][K] bf16
    const float* bias = blockIdx.z ? bias1 : bias0;
    float* C = blockIdx.z ? C1 : C0;

    __shared__ __align__(16) char smem[128 * 64 * 2 + 64 * 64 * 2]; // A 16K + B 8K
    char* As = smem;
    char* Bs = smem + 16384;

    const int t = threadIdx.x;
    const int lane = t & 63;
    const int wid = t >> 6;
    const int wm = wid >> 1, wn = wid & 1;
    const int row0 = blockIdx.x * 128;
    const int col0 = blockIdx.y * 64;
    const int nk = K >> 6;

    f32x4 acc[4][2];
    #pragma unroll
    for (int i = 0; i < 4; ++i)
        #pragma unroll
        for (int j = 0; j < 2; ++j)
            acc[i][j] = (f32x4){0.f, 0.f, 0.f, 0.f};

    uint4 stA[4]; uint4 stB[2];
    {
        #pragma unroll
        for (int i = 0; i < 4; ++i) {
            int c16 = t * 4 + i; int r = c16 >> 3, j = c16 & 7;
            int gr = row0 + r; if (gr > M - 1) gr = M - 1;
            stA[i] = *reinterpret_cast<const uint4*>(A + (size_t)gr * K + j * 8);
        }
        #pragma unroll
        for (int i = 0; i < 2; ++i) {
            int c16 = t * 2 + i; int n = c16 >> 3, j = c16 & 7;
            stB[i] = *reinterpret_cast<const uint4*>(Wt + (size_t)(col0 + n) * K + j * 8);
        }
    }

    for (int kt = 0; kt < nk; ++kt) {
        #pragma unroll
        for (int i = 0; i < 4; ++i) {
            int c16 = t * 4 + i; int r = c16 >> 3, j = c16 & 7;
            *reinterpret_cast<uint4*>(As + r * 128 + ((j ^ (r & 7)) << 4)) = stA[i];
        }
        #pragma unroll
        for (int i = 0; i < 2; ++i) {
            int c16 = t * 2 + i; int n = c16 >> 3, j = c16 & 7;
            *reinterpret_cast<uint4*>(Bs + n * 128 + ((j ^ (n & 7)) << 4)) = stB[i];
        }
        __syncthreads();
        if (kt + 1 < nk) {
            int ko = (kt + 1) * 64;
            #pragma unroll
            for (int i = 0; i < 4; ++i) {
                int c16 = t * 4 + i; int r = c16 >> 3, j = c16 & 7;
                int gr = row0 + r; if (gr > M - 1) gr = M - 1;
                stA[i] = *reinterpret_cast<const uint4*>(A + (size_t)gr * K + ko + j * 8);
            }
            #pragma unroll
            for (int i = 0; i < 2; ++i) {
                int c16 = t * 2 + i; int n = c16 >> 3, j = c16 & 7;
                stB[i] = *reinterpret_cast<const uint4*>(Wt + (size_t)(col0 + n) * K + ko + j * 8);
            }
        }
        #pragma unroll
        for (int kk = 0; kk < 2; ++kk) {
            bf16x8 a[4], b[2];
            const int kb2 = (kk * 32 + (lane >> 4) * 8) * 2;
            #pragma unroll
            for (int i = 0; i < 4; ++i) {
                int r = wm * 64 + i * 16 + (lane & 15);
                a[i] = *reinterpret_cast<const bf16x8*>(As + r * 128 + (kb2 ^ ((r & 7) << 4)));
            }
            #pragma unroll
            for (int j = 0; j < 2; ++j) {
                int n = wn * 32 + j * 16 + (lane & 15);
                b[j] = *reinterpret_cast<const bf16x8*>(Bs + n * 128 + (kb2 ^ ((n & 7) << 4)));
            }
            #pragma unroll
            for (int i = 0; i < 4; ++i)
                #pragma unroll
                for (int j = 0; j < 2; ++j)
                    acc[i][j] = __builtin_amdgcn_mfma_f32_16x16x32_bf16(a[i], b[j], acc[i][j], 0, 0, 0);
        }
        __syncthreads();
    }

    #pragma unroll
    for (int j = 0; j < 2; ++j) {
        int c = col0 + wn * 32 + j * 16 + (lane & 15);
        float bb = bias[c];
        #pragma unroll
        for (int i = 0; i < 4; ++i) {
            #pragma unroll
            for (int q = 0; q < 4; ++q) {
                int r = row0 + wm * 64 + i * 16 + (lane >> 4) * 4 + q;
                if (r < M) C[(size_t)r * No + c] = acc[i][j][q] + bb;
            }
        }
    }
}

// ---------------- CSR build ------------------------------------------------
__global__ void hist_kernel(const int* __restrict__ ei, int E, int Etot,
                            int* __restrict__ deg)
{
    int i = blockIdx.x * blockDim.x + threadIdx.x;
    if (i >= Etot) return;
    int d = (i < E) ? ei[E + i] : (i - E);
    atomicAdd(&deg[d], 1);
}

__global__ __launch_bounds__(1024) void scan_kernel(
    const int* __restrict__ deg, int* __restrict__ rowptr,
    int* __restrict__ cursor, int N)
{
    __shared__ int part[1024];
    const int t = threadIdx.x;
    const int chunk = (N + 1023) / 1024;
    const int lo = t * chunk;
    const int hi = (lo + chunk < N) ? lo + chunk : N;
    int s = 0;
    for (int i = lo; i < hi; ++i) s += deg[i];
    part[t] = s;
    __syncthreads();
    for (int off = 1; off < 1024; off <<= 1) {
        int v = (t >= off) ? part[t - off] : 0;
        __syncthreads();
        part[t] += v;
        __syncthreads();
    }
    int base = (t == 0) ? 0 : part[t - 1];
    for (int i = lo; i < hi; ++i) {
        rowptr[i] = base;
        cursor[i] = base;
        base += deg[i];
    }
    if (t == 1023) rowptr[N] = part[1023];
}

__global__ void scatter_kernel(const int* __restrict__ ei, int E, int Etot,
                               int* __restrict__ cursor, int* __restrict__ ssrc)
{
    int i = blockIdx.x * blockDim.x + threadIdx.x;
    if (i >= Etot) return;
    int d, s;
    if (i < E) { s = ei[i]; d = ei[E + i]; }
    else       { s = i - E; d = s; }
    int pos = atomicAdd(&cursor[d], 1);
    ssrc[pos] = s;
}

// ---------------- degree sort, contention-free ----------------------------
__global__ __launch_bounds__(256) void dhist2_kernel(
    const int* __restrict__ rowptr, int* __restrict__ blockHist, int N)
{
    __shared__ int lh[256];
    lh[threadIdx.x] = 0;
    __syncthreads();
    const int chunk = (N + SORT_BLOCKS - 1) / SORT_BLOCKS;
    const int lo = blockIdx.x * chunk;
    const int hi = (lo + chunk < N) ? lo + chunk : N;
    for (int d = lo + threadIdx.x; d < hi; d += 256) {
        int deg = rowptr[d + 1] - rowptr[d];
        atomicAdd(&lh[deg > 255 ? 255 : deg], 1);
    }
    __syncthreads();
    blockHist[blockIdx.x * 256 + threadIdx.x] = lh[threadIdx.x];
}

__global__ __launch_bounds__(256) void dscan2_kernel(
    const int* __restrict__ blockHist, int* __restrict__ blockOff)
{
    const int t = threadIdx.x;          // t = bin
    int total = 0;
    for (int b = 0; b < SORT_BLOCKS; ++b) total += blockHist[b * 256 + t];
    __shared__ int tmp[256];
    tmp[t] = total;
    __syncthreads();
    for (int off = 1; off < 256; off <<= 1) {
        int v = (t >= off) ? tmp[t - off] : 0;
        __syncthreads();
        tmp[t] += v;
        __syncthreads();
    }
    int start = (t == 0) ? 0 : tmp[t - 1];
    for (int b = 0; b < SORT_BLOCKS; ++b) {
        blockOff[b * 256 + t] = start;
        start += blockHist[b * 256 + t];
    }
}

__global__ __launch_bounds__(256) void dscatter2_kernel(
    const int* __restrict__ rowptr, const int* __restrict__ blockOff,
    int* __restrict__ dperm, int N)
{
    __shared__ int cur[256];
    cur[threadIdx.x] = blockOff[blockIdx.x * 256 + threadIdx.x];
    __syncthreads();
    const int chunk = (N + SORT_BLOCKS - 1) / SORT_BLOCKS;
    const int lo = blockIdx.x * chunk;
    const int hi = (lo + chunk < N) ? lo + chunk : N;
    for (int d = lo + threadIdx.x; d < hi; d += 256) {
        int deg = rowptr[d + 1] - rowptr[d];
        int pos = atomicAdd(&cur[deg > 255 ? 255 : deg], 1);
        dperm[pos] = d;
    }
}

// ---------------- fused edge kernel: 4-lane group per (dst, head) ---------
template <int H, bool OUT_F32, bool OUT_BF16>
__global__ __launch_bounds__(256) void gat_fused4(
    const int* __restrict__ rowptr, const int* __restrict__ ssrc,
    const int* __restrict__ dperm,
    const float* __restrict__ xl, const float* __restrict__ xr,
    const float* __restrict__ att, const float* __restrict__ bias,
    float* __restrict__ outf, unsigned short* __restrict__ outb, int N)
{
    const int gid = blockIdx.x * 64 + (threadIdx.x >> 2);
    const int sub = threadIdx.x & 3;
    if (gid >= N * H) return;
    const int di = gid / H;
    const int h  = gid - di * H;
    const int d  = dperm[di];
    const int HC = H * 64;
    const int co = h * 64 + sub * 16;

    float xrv[16], attv[16], acc[16];
    {
        const float* pr = xr + (size_t)d * HC + co;
        const float* pa = att + co;
        #pragma unroll
        for (int k = 0; k < 16; k += 4) {
            float4 v = *reinterpret_cast<const float4*>(pr + k);
            xrv[k] = v.x; xrv[k+1] = v.y; xrv[k+2] = v.z; xrv[k+3] = v.w;
            float4 w = *reinterpret_cast<const float4*>(pa + k);
            attv[k] = w.x; attv[k+1] = w.y; attv[k+2] = w.z; attv[k+3] = w.w;
        }
    }
    #pragma unroll
    for (int k = 0; k < 16; ++k) acc[k] = 0.f;
    float M = -3.0e38f, S = 0.f;

    const int begin = rowptr[d], end = rowptr[d + 1];
    int s = ssrc[begin];
    float cur[16];
    {
        const float* pl = xl + (size_t)s * HC + co;
        #pragma unroll
        for (int k = 0; k < 16; k += 4) {
            float4 v = *reinterpret_cast<const float4*>(pl + k);
            cur[k] = v.x; cur[k+1] = v.y; cur[k+2] = v.z; cur[k+3] = v.w;
        }
    }
    for (int e = begin; e < end; ++e) {
        float nxt[16];
        const bool more = (e + 1 < end);
        if (more) {
            int sn = ssrc[e + 1];
            const float* pl = xl + (size_t)sn * HC + co;
            #pragma unroll
            for (int k = 0; k < 16; k += 4) {
                float4 v = *reinterpret_cast<const float4*>(pl + k);
                nxt[k] = v.x; nxt[k+1] = v.y; nxt[k+2] = v.z; nxt[k+3] = v.w;
            }
        }
        float p = 0.f;
        #pragma unroll
        for (int k = 0; k < 16; ++k) {
            float v = cur[k] + xrv[k];
            v = fmaxf(v, 0.2f * v);
            p = fmaf(v, attv[k], p);
        }
        p += __shfl_xor(p, 1);
        p += __shfl_xor(p, 2);
        float nM = fmaxf(M, p);
        float scale = __expf(M - nM);
        float w = __expf(p - nM);
        S = fmaf(S, scale, w);
        #pragma unroll
        for (int k = 0; k < 16; ++k) acc[k] = fmaf(acc[k], scale, w * cur[k]);
        M = nM;
        if (more) {
            #pragma unroll
            for (int k = 0; k < 16; ++k) cur[k] = nxt[k];
        }
    }
    float inv = 1.f / S;
    const float* pb = bias + co;
    #pragma unroll
    for (int k = 0; k < 16; ++k) {
        float val = fmaf(acc[k], inv, pb[k]);
        acc[k] = val > 0.f ? val : 0.f;
    }
    size_t ob = (size_t)d * HC + co;
    if (OUT_F32) {
        #pragma unroll
        for (int k = 0; k < 16; k += 4) {
            float4 v = {acc[k], acc[k+1], acc[k+2], acc[k+3]};
            *reinterpret_cast<float4*>(outf + ob + k) = v;
        }
    }
    if (OUT_BF16) {
        unsigned pk[8];
        #pragma unroll
        for (int k = 0; k < 8; ++k)
            pk[k] = (unsigned)f2bf(acc[2*k]) | ((unsigned)f2bf(acc[2*k+1]) << 16);
        uint4 lo = {pk[0], pk[1], pk[2], pk[3]};
        uint4 hi = {pk[4], pk[5], pk[6], pk[7]};
        *reinterpret_cast<uint4*>(outb + ob) = lo;
        *reinterpret_cast<uint4*>(outb + ob + 8) = hi;
    }
}

// ---------------- segmented pool (batch sorted) + counts ------------------
__global__ __launch_bounds__(256) void pool_kernel2(
    const float* __restrict__ h3, const int* __restrict__ batch,
    float* __restrict__ sums, float* __restrict__ counts, int N)
{
    const int wave = blockIdx.x * 4 + (threadIdx.x >> 6);
    const int lane = threadIdx.x & 63;
    const int n0 = wave * 64;
    if (n0 >= N) return;
    const int n1 = (n0 + 64 < N) ? n0 + 64 : N;
    float s = 0.f, cnt = 0.f;
    int g = batch[n0];
    for (int n = n0; n < n1; ++n) {
        int gn = batch[n];
        if (gn != g) {
            atomicAdd(&sums[g * 64 + lane], s);
            if (lane == 0) atomicAdd(&counts[g], cnt);
            s = 0.f; cnt = 0.f; g = gn;
        }
        s += h3[(size_t)n * 64 + lane];
        cnt += 1.f;
    }
    atomicAdd(&sums[g * 64 + lane], s);
    if (lane == 0) atomicAdd(&counts[g], cnt);
}

// ---------------- MLP ------------------------------------------------------
__global__ __launch_bounds__(64) void mlp_kernel(
    const float* __restrict__ sums, const float* __restrict__ counts,
    const float* __restrict__ Wm1, const float* __restrict__ bm1,
    const float* __restrict__ Wm2, const float* __restrict__ bm2,
    float* __restrict__ out)
{
    int g = blockIdx.x;
    int t = threadIdx.x;
    __shared__ float pooled[64];
    __shared__ float hidden[32];
    float cnt = counts[g];
    cnt = cnt > 1.f ? cnt : 1.f;
    pooled[t] = sums[g * 64 + t] / cnt;
    __syncthreads();
    if (t < 32) {
        float a = bm1[t];
        #pragma unroll
        for (int k = 0; k < 64; ++k) a = fmaf(pooled[k], Wm1[k * 32 + t], a);
        hidden[t] = a > 0.f ? a : 0.f;
    }
    __syncthreads();
    if (t < 2) {
        float a = bm2[t];
        #pragma unroll
        for (int j = 0; j < 32; ++j) a = fmaf(hidden[j], Wm2[j * 2 + t], a);
        out[g * 2 + t] = a;
    }
}

// ---------------- layer driver ---------------------------------------------
static void run_layer(const unsigned short* Xb, int K, int H,
                      const float* Wl, const float* bl,
                      const float* Wr, const float* br,
                      const float* att, const float* bias_out,
                      unsigned short* Wtl, unsigned short* Wtr,
                      const int* rowptr, const int* ssrc, const int* dperm, int N,
                      float* xl, float* xr, float* houtf, unsigned short* houtb,
                      hipStream_t stream)
{
    const int No = H * 64;
    const int nw = K * No;
    cvt_wt_kernel<<<(nw + 255) / 256, 256, 0, stream>>>(Wl, Wtl, K, No);
    cvt_wt_kernel<<<(nw + 255) / 256, 256, 0, stream>>>(Wr, Wtr, K, No);
    dim3 g((N + 127) / 128, No / 64, 2);
    gemm_mfma<<<g, 256, 0, stream>>>(Xb, Wtl, Wtr, bl, br, xl, xr, N, No, K);

    int ngroups = N * H;
    int blocks = (ngroups + 63) / 64;
    if (H == 4)
        gat_fused4<4, false, true><<<blocks, 256, 0, stream>>>(
            rowptr, ssrc, dperm, xl, xr, att, bias_out, houtf, houtb, N);
    else if (H == 2)
        gat_fused4<2, false, true><<<blocks, 256, 0, stream>>>(
            rowptr, ssrc, dperm, xl, xr, att, bias_out, houtf, houtb, N);
    else
        gat_fused4<1, true, false><<<blocks, 256, 0, stream>>>(
            rowptr, ssrc, dperm, xl, xr, att, bias_out, houtf, houtb, N);
}

extern "C" void kernel_launch(void* const* d_in, const int* in_sizes, int n_in,
                              void* d_out, int out_size, void* d_ws, size_t ws_size,
                              hipStream_t stream)
{
    const float* x    = (const float*)d_in[0];
    const int*   ei   = (const int*)d_in[1];
    const int*   batch= (const int*)d_in[2];
    const float* Wl1 = (const float*)d_in[3];
    const float* bl1 = (const float*)d_in[4];
    const float* Wr1 = (const float*)d_in[5];
    const float* br1 = (const float*)d_in[6];
    const float* att1= (const float*)d_in[7];
    const float* b1  = (const float*)d_in[8];
    const float* Wl2 = (const float*)d_in[9];
    const float* bl2 = (const float*)d_in[10];
    const float* Wr2 = (const float*)d_in[11];
    const float* br2 = (const float*)d_in[12];
    const float* att2= (const float*)d_in[13];
    const float* b2  = (const float*)d_in[14];
    const float* Wl3 = (const float*)d_in[15];
    const float* bl3 = (const float*)d_in[16];
    const float* Wr3 = (const float*)d_in[17];
    const float* br3 = (const float*)d_in[18];
    const float* att3= (const float*)d_in[19];
    const float* b3  = (const float*)d_in[20];
    const float* Wm1 = (const float*)d_in[21];
    const float* bm1 = (const float*)d_in[22];
    const float* Wm2 = (const float*)d_in[23];
    const float* bm2 = (const float*)d_in[24];

    const int N    = in_sizes[2];          // 50000
    const int E    = in_sizes[1] / 2;      // 800000
    const int Etot = E + N;                // + self loops
    const int K1   = in_sizes[0] / N;      // 128

    // workspace layout
    char* wsb = (char*)d_ws;
    size_t o = 0;
    auto alloc = [&](size_t bytes) { char* p = wsb + o; o += (bytes + 255) & ~(size_t)255; return p; };
    float*          xl    = (float*)alloc((size_t)N * 256 * 4);
    float*          xr    = (float*)alloc((size_t)N * 256 * 4);
    unsigned short* xb    = (unsigned short*)alloc((size_t)N * K1 * 2);
    unsigned short* h1b   = (unsigned short*)alloc((size_t)N * 256 * 2);
    unsigned short* h2b   = (unsigned short*)alloc((size_t)N * 128 * 2);
    float*          h3f   = (float*)alloc((size_t)N * 64 * 4);
    int*   deg    = (int*)alloc((size_t)N * 4);
    int*   rowptr = (int*)alloc((size_t)(N + 1) * 4);
    int*   cursor = (int*)alloc((size_t)N * 4);
    int*   ssrc   = (int*)alloc((size_t)Etot * 4);
    int*   dperm  = (int*)alloc((size_t)N * 4);
    int*   blockHist = (int*)alloc((size_t)SORT_BLOCKS * 256 * 4);
    int*   blockOff  = (int*)alloc((size_t)SORT_BLOCKS * 256 * 4);
    unsigned short* Wtl = (unsigned short*)alloc(256 * 256 * 2);
    unsigned short* Wtr = (unsigned short*)alloc(256 * 256 * 2);
    float* sums   = (float*)alloc(64 * 64 * 4);
    float* counts = (float*)alloc(64 * 4);
    (void)ws_size; (void)n_in; (void)out_size;

    // ---- CSR build + degree sort (shared by all 3 layers) ----
    hipMemsetAsync(deg, 0, (size_t)N * 4, stream);
    hist_kernel<<<(Etot + 255) / 256, 256, 0, stream>>>(ei, E, Etot, deg);
    scan_kernel<<<1, 1024, 0, stream>>>(deg, rowptr, cursor, N);
    scatter_kernel<<<(Etot + 255) / 256, 256, 0, stream>>>(ei, E, Etot, cursor, ssrc);
    dhist2_kernel<<<SORT_BLOCKS, 256, 0, stream>>>(rowptr, blockHist, N);
    dscan2_kernel<<<1, 256, 0, stream>>>(blockHist, blockOff);
    dscatter2_kernel<<<SORT_BLOCKS, 256, 0, stream>>>(rowptr, blockOff, dperm, N);

    // ---- convert input x to bf16 ----
    cvt_kernel<<<((N * K1) / 4 + 255) / 256, 256, 0, stream>>>(x, xb, N * K1);

    // ---- layers ----
    run_layer(xb, K1, 4, Wl1, bl1, Wr1, br1, att1, b1, Wtl, Wtr,
              rowptr, ssrc, dperm, N, xl, xr, nullptr, h1b, stream);
    run_layer(h1b, 256, 2, Wl2, bl2, Wr2, br2, att2, b2, Wtl, Wtr,
              rowptr, ssrc, dperm, N, xl, xr, nullptr, h2b, stream);
    run_layer(h2b, 128, 1, Wl3, bl3, Wr3, br3, att3, b3, Wtl, Wtr,
              rowptr, ssrc, dperm, N, xl, xr, h3f, nullptr, stream);

    // ---- pool + MLP ----
    hipMemsetAsync(sums, 0, 64 * 64 * 4, stream);
    hipMemsetAsync(counts, 0, 64 * 4, stream);
    {
        int waves = (N + 63) / 64;
        pool_kernel2<<<(waves + 3) / 4, 256, 0, stream>>>(h3f, batch, sums, counts, N);
    }
    mlp_kernel<<<64, 64, 0, stream>>>(sums, counts, Wm1, bm1, Wm2, bm2, (float*)d_out);
}

// Round 5
// 602.625 us; speedup vs baseline: 4.7470x; 1.1398x over previous
//
#include <hip/hip_runtime.h>

// GATv2 GNN classifier.
// R5: xl stored bf16 (written directly by GEMM epilogue) -> edge-phase gather
// bytes halved (128B/line per (dst,head) slice). xr stays fp32 (logits only).
// Rest: bf16 MFMA GEMMs, 4-lane-group fused edge kernel, contention-free sort.

typedef __attribute__((ext_vector_type(8))) short bf16x8;
typedef __attribute__((ext_vector_type(4))) float f32x4;

#define SORT_BLOCKS 128

__device__ inline unsigned short f2bf(float f) {
    unsigned u = __float_as_uint(f);
    unsigned r = (u + 0x7fff + ((u >> 16) & 1)) >> 16;   // RNE
    return (unsigned short)r;
}

// unpack 8 bf16 (uint4, mem order lo=even) into 8 floats
__device__ inline void unpack8(uint4 a, float* d) {
    d[0] = __uint_as_float(a.x << 16); d[1] = __uint_as_float(a.x & 0xffff0000u);
    d[2] = __uint_as_float(a.y << 16); d[3] = __uint_as_float(a.y & 0xffff0000u);
    d[4] = __uint_as_float(a.z << 16); d[5] = __uint_as_float(a.z & 0xffff0000u);
    d[6] = __uint_as_float(a.w << 16); d[7] = __uint_as_float(a.w & 0xffff0000u);
}

// ---------------- fp32 -> bf16 elementwise convert ------------------------
__global__ void cvt_kernel(const float* __restrict__ in,
                           unsigned short* __restrict__ out, int n)
{
    int i = (blockIdx.x * blockDim.x + threadIdx.x) * 4;
    if (i >= n) return;
    float4 v = *reinterpret_cast<const float4*>(in + i);
    ushort4 o;
    o.x = f2bf(v.x); o.y = f2bf(v.y); o.z = f2bf(v.z); o.w = f2bf(v.w);
    *reinterpret_cast<ushort4*>(out + i) = o;
}

// ---------------- W [K][No] fp32 -> Wt [No][K] bf16 -----------------------
__global__ void cvt_wt_kernel(const float* __restrict__ W,
                              unsigned short* __restrict__ Wt, int K, int No)
{
    int idx = blockIdx.x * blockDim.x + threadIdx.x;
    if (idx >= K * No) return;
    int n = idx / K, k = idx - n * K;
    Wt[idx] = f2bf(W[(size_t)k * No + n]);
}

// ---------------- MFMA GEMM ------------------------------------------------
// z=0: A*W0 + bias0 -> Cb (bf16);  z=1: A*W1 + bias1 -> Cf (f32)
__global__ __launch_bounds__(256) void gemm_mfma(
    const unsigned short* __restrict__ A,     // [M][K] bf16
    const unsigned short* __restrict__ W0, const unsigned short* __restrict__ W1,
    const float* __restrict__ bias0, const float* __restrict__ bias1,
    unsigned short* __restrict__ Cb, float* __restrict__ Cf,
    int M, int No, int K)
{
    const unsigned short* Wt = blockIdx.z ? W1 : W0;  // [No][K] bf16
    const float* bias = blockIdx.z ? bias1 : bias0;

    __shared__ __align__(16) char smem[128 * 64 * 2 + 64 * 64 * 2]; // A 16K + B 8K
    char* As = smem;
    char* Bs = smem + 16384;

    const int t = threadIdx.x;
    const int lane = t & 63;
    const int wid = t >> 6;
    const int wm = wid >> 1, wn = wid & 1;
    const int row0 = blockIdx.x * 128;
    const int col0 = blockIdx.y * 64;
    const int nk = K >> 6;

    f32x4 acc[4][2];
    #pragma unroll
    for (int i = 0; i < 4; ++i)
        #pragma unroll
        for (int j = 0; j < 2; ++j)
            acc[i][j] = (f32x4){0.f, 0.f, 0.f, 0.f};

    uint4 stA[4]; uint4 stB[2];
    {
        #pragma unroll
        for (int i = 0; i < 4; ++i) {
            int c16 = t * 4 + i; int r = c16 >> 3, j = c16 & 7;
            int gr = row0 + r; if (gr > M - 1) gr = M - 1;
            stA[i] = *reinterpret_cast<const uint4*>(A + (size_t)gr * K + j * 8);
        }
        #pragma unroll
        for (int i = 0; i < 2; ++i) {
            int c16 = t * 2 + i; int n = c16 >> 3, j = c16 & 7;
            stB[i] = *reinterpret_cast<const uint4*>(Wt + (size_t)(col0 + n) * K + j * 8);
        }
    }

    for (int kt = 0; kt < nk; ++kt) {
        #pragma unroll
        for (int i = 0; i < 4; ++i) {
            int c16 = t * 4 + i; int r = c16 >> 3, j = c16 & 7;
            *reinterpret_cast<uint4*>(As + r * 128 + ((j ^ (r & 7)) << 4)) = stA[i];
        }
        #pragma unroll
        for (int i = 0; i < 2; ++i) {
            int c16 = t * 2 + i; int n = c16 >> 3, j = c16 & 7;
            *reinterpret_cast<uint4*>(Bs + n * 128 + ((j ^ (n & 7)) << 4)) = stB[i];
        }
        __syncthreads();
        if (kt + 1 < nk) {
            int ko = (kt + 1) * 64;
            #pragma unroll
            for (int i = 0; i < 4; ++i) {
                int c16 = t * 4 + i; int r = c16 >> 3, j = c16 & 7;
                int gr = row0 + r; if (gr > M - 1) gr = M - 1;
                stA[i] = *reinterpret_cast<const uint4*>(A + (size_t)gr * K + ko + j * 8);
            }
            #pragma unroll
            for (int i = 0; i < 2; ++i) {
                int c16 = t * 2 + i; int n = c16 >> 3, j = c16 & 7;
                stB[i] = *reinterpret_cast<const uint4*>(Wt + (size_t)(col0 + n) * K + ko + j * 8);
            }
        }
        #pragma unroll
        for (int kk = 0; kk < 2; ++kk) {
            bf16x8 a[4], b[2];
            const int kb2 = (kk * 32 + (lane >> 4) * 8) * 2;
            #pragma unroll
            for (int i = 0; i < 4; ++i) {
                int r = wm * 64 + i * 16 + (lane & 15);
                a[i] = *reinterpret_cast<const bf16x8*>(As + r * 128 + (kb2 ^ ((r & 7) << 4)));
            }
            #pragma unroll
            for (int j = 0; j < 2; ++j) {
                int n = wn * 32 + j * 16 + (lane & 15);
                b[j] = *reinterpret_cast<const bf16x8*>(Bs + n * 128 + (kb2 ^ ((n & 7) << 4)));
            }
            #pragma unroll
            for (int i = 0; i < 4; ++i)
                #pragma unroll
                for (int j = 0; j < 2; ++j)
                    acc[i][j] = __builtin_amdgcn_mfma_f32_16x16x32_bf16(a[i], b[j], acc[i][j], 0, 0, 0);
        }
        __syncthreads();
    }

    const bool isB = (blockIdx.z == 0);
    #pragma unroll
    for (int j = 0; j < 2; ++j) {
        int c = col0 + wn * 32 + j * 16 + (lane & 15);
        float bb = bias[c];
        #pragma unroll
        for (int i = 0; i < 4; ++i) {
            #pragma unroll
            for (int q = 0; q < 4; ++q) {
                int r = row0 + wm * 64 + i * 16 + (lane >> 4) * 4 + q;
                if (r < M) {
                    float v = acc[i][j][q] + bb;
                    if (isB) Cb[(size_t)r * No + c] = f2bf(v);
                    else     Cf[(size_t)r * No + c] = v;
                }
            }
        }
    }
}

// ---------------- CSR build ------------------------------------------------
__global__ void hist_kernel(const int* __restrict__ ei, int E, int Etot,
                            int* __restrict__ deg)
{
    int i = blockIdx.x * blockDim.x + threadIdx.x;
    if (i >= Etot) return;
    int d = (i < E) ? ei[E + i] : (i - E);
    atomicAdd(&deg[d], 1);
}

__global__ __launch_bounds__(1024) void scan_kernel(
    const int* __restrict__ deg, int* __restrict__ rowptr,
    int* __restrict__ cursor, int N)
{
    __shared__ int part[1024];
    const int t = threadIdx.x;
    const int chunk = (N + 1023) / 1024;
    const int lo = t * chunk;
    const int hi = (lo + chunk < N) ? lo + chunk : N;
    int s = 0;
    for (int i = lo; i < hi; ++i) s += deg[i];
    part[t] = s;
    __syncthreads();
    for (int off = 1; off < 1024; off <<= 1) {
        int v = (t >= off) ? part[t - off] : 0;
        __syncthreads();
        part[t] += v;
        __syncthreads();
    }
    int base = (t == 0) ? 0 : part[t - 1];
    for (int i = lo; i < hi; ++i) {
        rowptr[i] = base;
        cursor[i] = base;
        base += deg[i];
    }
    if (t == 1023) rowptr[N] = part[1023];
}

__global__ void scatter_kernel(const int* __restrict__ ei, int E, int Etot,
                               int* __restrict__ cursor, int* __restrict__ ssrc)
{
    int i = blockIdx.x * blockDim.x + threadIdx.x;
    if (i >= Etot) return;
    int d, s;
    if (i < E) { s = ei[i]; d = ei[E + i]; }
    else       { s = i - E; d = s; }
    int pos = atomicAdd(&cursor[d], 1);
    ssrc[pos] = s;
}

// ---------------- degree sort, contention-free ----------------------------
__global__ __launch_bounds__(256) void dhist2_kernel(
    const int* __restrict__ rowptr, int* __restrict__ blockHist, int N)
{
    __shared__ int lh[256];
    lh[threadIdx.x] = 0;
    __syncthreads();
    const int chunk = (N + SORT_BLOCKS - 1) / SORT_BLOCKS;
    const int lo = blockIdx.x * chunk;
    const int hi = (lo + chunk < N) ? lo + chunk : N;
    for (int d = lo + threadIdx.x; d < hi; d += 256) {
        int deg = rowptr[d + 1] - rowptr[d];
        atomicAdd(&lh[deg > 255 ? 255 : deg], 1);
    }
    __syncthreads();
    blockHist[blockIdx.x * 256 + threadIdx.x] = lh[threadIdx.x];
}

__global__ __launch_bounds__(256) void dscan2_kernel(
    const int* __restrict__ blockHist, int* __restrict__ blockOff)
{
    const int t = threadIdx.x;          // t = bin
    int total = 0;
    for (int b = 0; b < SORT_BLOCKS; ++b) total += blockHist[b * 256 + t];
    __shared__ int tmp[256];
    tmp[t] = total;
    __syncthreads();
    for (int off = 1; off < 256; off <<= 1) {
        int v = (t >= off) ? tmp[t - off] : 0;
        __syncthreads();
        tmp[t] += v;
        __syncthreads();
    }
    int start = (t == 0) ? 0 : tmp[t - 1];
    for (int b = 0; b < SORT_BLOCKS; ++b) {
        blockOff[b * 256 + t] = start;
        start += blockHist[b * 256 + t];
    }
}

__global__ __launch_bounds__(256) void dscatter2_kernel(
    const int* __restrict__ rowptr, const int* __restrict__ blockOff,
    int* __restrict__ dperm, int N)
{
    __shared__ int cur[256];
    cur[threadIdx.x] = blockOff[blockIdx.x * 256 + threadIdx.x];
    __syncthreads();
    const int chunk = (N + SORT_BLOCKS - 1) / SORT_BLOCKS;
    const int lo = blockIdx.x * chunk;
    const int hi = (lo + chunk < N) ? lo + chunk : N;
    for (int d = lo + threadIdx.x; d < hi; d += 256) {
        int deg = rowptr[d + 1] - rowptr[d];
        int pos = atomicAdd(&cur[deg > 255 ? 255 : deg], 1);
        dperm[pos] = d;
    }
}

// ---------------- fused edge kernel: 4-lane group per (dst, head) ---------
// xl is bf16 [N][HC]; xr fp32 [N][HC].
template <int H, bool OUT_F32, bool OUT_BF16>
__global__ __launch_bounds__(256) void gat_fused4(
    const int* __restrict__ rowptr, const int* __restrict__ ssrc,
    const int* __restrict__ dperm,
    const unsigned short* __restrict__ xl, const float* __restrict__ xr,
    const float* __restrict__ att, const float* __restrict__ bias,
    float* __restrict__ outf, unsigned short* __restrict__ outb, int N)
{
    const int gid = blockIdx.x * 64 + (threadIdx.x >> 2);
    const int sub = threadIdx.x & 3;
    if (gid >= N * H) return;
    const int di = gid / H;
    const int h  = gid - di * H;
    const int d  = dperm[di];
    const int HC = H * 64;
    const int co = h * 64 + sub * 16;

    float xrv[16], attv[16], acc[16];
    {
        const float* pr = xr + (size_t)d * HC + co;
        const float* pa = att + co;
        #pragma unroll
        for (int k = 0; k < 16; k += 4) {
            float4 v = *reinterpret_cast<const float4*>(pr + k);
            xrv[k] = v.x; xrv[k+1] = v.y; xrv[k+2] = v.z; xrv[k+3] = v.w;
            float4 w = *reinterpret_cast<const float4*>(pa + k);
            attv[k] = w.x; attv[k+1] = w.y; attv[k+2] = w.z; attv[k+3] = w.w;
        }
    }
    #pragma unroll
    for (int k = 0; k < 16; ++k) acc[k] = 0.f;
    float M = -3.0e38f, S = 0.f;

    const int begin = rowptr[d], end = rowptr[d + 1];
    uint4 c0, c1;
    {
        const unsigned short* pl = xl + (size_t)ssrc[begin] * HC + co;
        c0 = *reinterpret_cast<const uint4*>(pl);
        c1 = *reinterpret_cast<const uint4*>(pl + 8);
    }
    for (int e = begin; e < end; ++e) {
        uint4 n0, n1;
        const bool more = (e + 1 < end);
        if (more) {
            const unsigned short* pl = xl + (size_t)ssrc[e + 1] * HC + co;
            n0 = *reinterpret_cast<const uint4*>(pl);
            n1 = *reinterpret_cast<const uint4*>(pl + 8);
        }
        float cur[16];
        unpack8(c0, cur);
        unpack8(c1, cur + 8);
        float p = 0.f;
        #pragma unroll
        for (int k = 0; k < 16; ++k) {
            float v = cur[k] + xrv[k];
            v = fmaxf(v, 0.2f * v);           // leaky_relu 0.2
            p = fmaf(v, attv[k], p);
        }
        p += __shfl_xor(p, 1);
        p += __shfl_xor(p, 2);
        float nM = fmaxf(M, p);
        float scale = __expf(M - nM);
        float w = __expf(p - nM);
        S = fmaf(S, scale, w);
        #pragma unroll
        for (int k = 0; k < 16; ++k) acc[k] = fmaf(acc[k], scale, w * cur[k]);
        M = nM;
        if (more) { c0 = n0; c1 = n1; }
    }
    float inv = 1.f / S;
    const float* pb = bias + co;
    #pragma unroll
    for (int k = 0; k < 16; ++k) {
        float val = fmaf(acc[k], inv, pb[k]);
        acc[k] = val > 0.f ? val : 0.f;
    }
    size_t ob = (size_t)d * HC + co;
    if (OUT_F32) {
        #pragma unroll
        for (int k = 0; k < 16; k += 4) {
            float4 v = {acc[k], acc[k+1], acc[k+2], acc[k+3]};
            *reinterpret_cast<float4*>(outf + ob + k) = v;
        }
    }
    if (OUT_BF16) {
        unsigned pk[8];
        #pragma unroll
        for (int k = 0; k < 8; ++k)
            pk[k] = (unsigned)f2bf(acc[2*k]) | ((unsigned)f2bf(acc[2*k+1]) << 16);
        uint4 lo = {pk[0], pk[1], pk[2], pk[3]};
        uint4 hi = {pk[4], pk[5], pk[6], pk[7]};
        *reinterpret_cast<uint4*>(outb + ob) = lo;
        *reinterpret_cast<uint4*>(outb + ob + 8) = hi;
    }
}

// ---------------- segmented pool (batch sorted) + counts ------------------
__global__ __launch_bounds__(256) void pool_kernel2(
    const float* __restrict__ h3, const int* __restrict__ batch,
    float* __restrict__ sums, float* __restrict__ counts, int N)
{
    const int wave = blockIdx.x * 4 + (threadIdx.x >> 6);
    const int lane = threadIdx.x & 63;
    const int n0 = wave * 64;
    if (n0 >= N) return;
    const int n1 = (n0 + 64 < N) ? n0 + 64 : N;
    float s = 0.f, cnt = 0.f;
    int g = batch[n0];
    for (int n = n0; n < n1; ++n) {
        int gn = batch[n];
        if (gn != g) {
            atomicAdd(&sums[g * 64 + lane], s);
            if (lane == 0) atomicAdd(&counts[g], cnt);
            s = 0.f; cnt = 0.f; g = gn;
        }
        s += h3[(size_t)n * 64 + lane];
        cnt += 1.f;
    }
    atomicAdd(&sums[g * 64 + lane], s);
    if (lane == 0) atomicAdd(&counts[g], cnt);
}

// ---------------- MLP ------------------------------------------------------
__global__ __launch_bounds__(64) void mlp_kernel(
    const float* __restrict__ sums, const float* __restrict__ counts,
    const float* __restrict__ Wm1, const float* __restrict__ bm1,
    const float* __restrict__ Wm2, const float* __restrict__ bm2,
    float* __restrict__ out)
{
    int g = blockIdx.x;
    int t = threadIdx.x;
    __shared__ float pooled[64];
    __shared__ float hidden[32];
    float cnt = counts[g];
    cnt = cnt > 1.f ? cnt : 1.f;
    pooled[t] = sums[g * 64 + t] / cnt;
    __syncthreads();
    if (t < 32) {
        float a = bm1[t];
        #pragma unroll
        for (int k = 0; k < 64; ++k) a = fmaf(pooled[k], Wm1[k * 32 + t], a);
        hidden[t] = a > 0.f ? a : 0.f;
    }
    __syncthreads();
    if (t < 2) {
        float a = bm2[t];
        #pragma unroll
        for (int j = 0; j < 32; ++j) a = fmaf(hidden[j], Wm2[j * 2 + t], a);
        out[g * 2 + t] = a;
    }
}

// ---------------- layer driver ---------------------------------------------
static void run_layer(const unsigned short* Xb, int K, int H,
                      const float* Wl, const float* bl,
                      const float* Wr, const float* br,
                      const float* att, const float* bias_out,
                      unsigned short* Wtl, unsigned short* Wtr,
                      const int* rowptr, const int* ssrc, const int* dperm, int N,
                      unsigned short* xl, float* xr,
                      float* houtf, unsigned short* houtb,
                      hipStream_t stream)
{
    const int No = H * 64;
    const int nw = K * No;
    cvt_wt_kernel<<<(nw + 255) / 256, 256, 0, stream>>>(Wl, Wtl, K, No);
    cvt_wt_kernel<<<(nw + 255) / 256, 256, 0, stream>>>(Wr, Wtr, K, No);
    dim3 g((N + 127) / 128, No / 64, 2);
    gemm_mfma<<<g, 256, 0, stream>>>(Xb, Wtl, Wtr, bl, br, xl, xr, N, No, K);

    int ngroups = N * H;
    int blocks = (ngroups + 63) / 64;
    if (H == 4)
        gat_fused4<4, false, true><<<blocks, 256, 0, stream>>>(
            rowptr, ssrc, dperm, xl, xr, att, bias_out, houtf, houtb, N);
    else if (H == 2)
        gat_fused4<2, false, true><<<blocks, 256, 0, stream>>>(
            rowptr, ssrc, dperm, xl, xr, att, bias_out, houtf, houtb, N);
    else
        gat_fused4<1, true, false><<<blocks, 256, 0, stream>>>(
            rowptr, ssrc, dperm, xl, xr, att, bias_out, houtf, houtb, N);
}

extern "C" void kernel_launch(void* const* d_in, const int* in_sizes, int n_in,
                              void* d_out, int out_size, void* d_ws, size_t ws_size,
                              hipStream_t stream)
{
    const float* x    = (const float*)d_in[0];
    const int*   ei   = (const int*)d_in[1];
    const int*   batch= (const int*)d_in[2];
    const float* Wl1 = (const float*)d_in[3];
    const float* bl1 = (const float*)d_in[4];
    const float* Wr1 = (const float*)d_in[5];
    const float* br1 = (const float*)d_in[6];
    const float* att1= (const float*)d_in[7];
    const float* b1  = (const float*)d_in[8];
    const float* Wl2 = (const float*)d_in[9];
    const float* bl2 = (const float*)d_in[10];
    const float* Wr2 = (const float*)d_in[11];
    const float* br2 = (const float*)d_in[12];
    const float* att2= (const float*)d_in[13];
    const float* b2  = (const float*)d_in[14];
    const float* Wl3 = (const float*)d_in[15];
    const float* bl3 = (const float*)d_in[16];
    const float* Wr3 = (const float*)d_in[17];
    const float* br3 = (const float*)d_in[18];
    const float* att3= (const float*)d_in[19];
    const float* b3  = (const float*)d_in[20];
    const float* Wm1 = (const float*)d_in[21];
    const float* bm1 = (const float*)d_in[22];
    const float* Wm2 = (const float*)d_in[23];
    const float* bm2 = (const float*)d_in[24];

    const int N    = in_sizes[2];          // 50000
    const int E    = in_sizes[1] / 2;      // 800000
    const int Etot = E + N;                // + self loops
    const int K1   = in_sizes[0] / N;      // 128

    // workspace layout
    char* wsb = (char*)d_ws;
    size_t o = 0;
    auto alloc = [&](size_t bytes) { char* p = wsb + o; o += (bytes + 255) & ~(size_t)255; return p; };
    unsigned short* xl    = (unsigned short*)alloc((size_t)N * 256 * 2);
    float*          xr    = (float*)alloc((size_t)N * 256 * 4);
    unsigned short* xb    = (unsigned short*)alloc((size_t)N * K1 * 2);
    unsigned short* h1b   = (unsigned short*)alloc((size_t)N * 256 * 2);
    unsigned short* h2b   = (unsigned short*)alloc((size_t)N * 128 * 2);
    float*          h3f   = (float*)alloc((size_t)N * 64 * 4);
    int*   deg    = (int*)alloc((size_t)N * 4);
    int*   rowptr = (int*)alloc((size_t)(N + 1) * 4);
    int*   cursor = (int*)alloc((size_t)N * 4);
    int*   ssrc   = (int*)alloc((size_t)Etot * 4);
    int*   dperm  = (int*)alloc((size_t)N * 4);
    int*   blockHist = (int*)alloc((size_t)SORT_BLOCKS * 256 * 4);
    int*   blockOff  = (int*)alloc((size_t)SORT_BLOCKS * 256 * 4);
    unsigned short* Wtl = (unsigned short*)alloc(256 * 256 * 2);
    unsigned short* Wtr = (unsigned short*)alloc(256 * 256 * 2);
    float* sums   = (float*)alloc(64 * 64 * 4);
    float* counts = (float*)alloc(64 * 4);
    (void)ws_size; (void)n_in; (void)out_size;

    // ---- CSR build + degree sort (shared by all 3 layers) ----
    hipMemsetAsync(deg, 0, (size_t)N * 4, stream);
    hist_kernel<<<(Etot + 255) / 256, 256, 0, stream>>>(ei, E, Etot, deg);
    scan_kernel<<<1, 1024, 0, stream>>>(deg, rowptr, cursor, N);
    scatter_kernel<<<(Etot + 255) / 256, 256, 0, stream>>>(ei, E, Etot, cursor, ssrc);
    dhist2_kernel<<<SORT_BLOCKS, 256, 0, stream>>>(rowptr, blockHist, N);
    dscan2_kernel<<<1, 256, 0, stream>>>(blockHist, blockOff);
    dscatter2_kernel<<<SORT_BLOCKS, 256, 0, stream>>>(rowptr, blockOff, dperm, N);

    // ---- convert input x to bf16 ----
    cvt_kernel<<<((N * K1) / 4 + 255) / 256, 256, 0, stream>>>(x, xb, N * K1);

    // ---- layers ----
    run_layer(xb, K1, 4, Wl1, bl1, Wr1, br1, att1, b1, Wtl, Wtr,
              rowptr, ssrc, dperm, N, xl, xr, nullptr, h1b, stream);
    run_layer(h1b, 256, 2, Wl2, bl2, Wr2, br2, att2, b2, Wtl, Wtr,
              rowptr, ssrc, dperm, N, xl, xr, nullptr, h2b, stream);
    run_layer(h2b, 128, 1, Wl3, bl3, Wr3, br3, att3, b3, Wtl, Wtr,
              rowptr, ssrc, dperm, N, xl, xr, h3f, nullptr, stream);

    // ---- pool + MLP ----
    hipMemsetAsync(sums, 0, 64 * 64 * 4, stream);
    hipMemsetAsync(counts, 0, 64 * 4, stream);
    {
        int waves = (N + 63) / 64;
        pool_kernel2<<<(waves + 3) / 4, 256, 0, stream>>>(h3f, batch, sums, counts, N);
    }
    mlp_kernel<<<64, 64, 0, stream>>>(sums, counts, Wm1, bm1, Wm2, bm2, (float*)d_out);
}

// Round 6
// 494.118 us; speedup vs baseline: 5.7894x; 1.2196x over previous
//
#include <hip/hip_runtime.h>

// GATv2 GNN classifier.
// R6: 3-phase coalesced device-wide scan (replaces 108us single-block scan);
// SORT_BLOCKS 128->64; all weight converts in one launch.
// Rest: bf16 MFMA GEMMs, bf16 xl gather, 4-lane-group fused edge kernel.

typedef __attribute__((ext_vector_type(8))) short bf16x8;
typedef __attribute__((ext_vector_type(4))) float f32x4;

#define SORT_BLOCKS 64
#define SCAN_BLOCKS 256

__device__ inline unsigned short f2bf(float f) {
    unsigned u = __float_as_uint(f);
    unsigned r = (u + 0x7fff + ((u >> 16) & 1)) >> 16;   // RNE
    return (unsigned short)r;
}

__device__ inline void unpack8(uint4 a, float* d) {
    d[0] = __uint_as_float(a.x << 16); d[1] = __uint_as_float(a.x & 0xffff0000u);
    d[2] = __uint_as_float(a.y << 16); d[3] = __uint_as_float(a.y & 0xffff0000u);
    d[4] = __uint_as_float(a.z << 16); d[5] = __uint_as_float(a.z & 0xffff0000u);
    d[6] = __uint_as_float(a.w << 16); d[7] = __uint_as_float(a.w & 0xffff0000u);
}

// ---------------- fp32 -> bf16 elementwise convert ------------------------
__global__ void cvt_kernel(const float* __restrict__ in,
                           unsigned short* __restrict__ out, int n)
{
    int i = (blockIdx.x * blockDim.x + threadIdx.x) * 4;
    if (i >= n) return;
    float4 v = *reinterpret_cast<const float4*>(in + i);
    ushort4 o;
    o.x = f2bf(v.x); o.y = f2bf(v.y); o.z = f2bf(v.z); o.w = f2bf(v.w);
    *reinterpret_cast<ushort4*>(out + i) = o;
}

// ---------------- all six W [K][No] fp32 -> Wt [No][K] bf16, one launch ----
__global__ void cvt_wt_all_kernel(
    const float* __restrict__ Wl1, const float* __restrict__ Wr1, unsigned short* __restrict__ T1l, unsigned short* __restrict__ T1r,
    const float* __restrict__ Wl2, const float* __restrict__ Wr2, unsigned short* __restrict__ T2l, unsigned short* __restrict__ T2r,
    const float* __restrict__ Wl3, const float* __restrict__ Wr3, unsigned short* __restrict__ T3l, unsigned short* __restrict__ T3r)
{
    int id = blockIdx.x * blockDim.x + threadIdx.x;
    const float* W; unsigned short* T; int K, No, idx;
    if (id < 2 * 32768) {            // layer1: 128x256
        K = 128; No = 256; idx = id & 32767;
        W = (id < 32768) ? Wl1 : Wr1; T = (id < 32768) ? T1l : T1r;
    } else if (id < 2 * 32768 + 2 * 32768) {  // layer2: 256x128
        int v = id - 65536; K = 256; No = 128; idx = v & 32767;
        W = (v < 32768) ? Wl2 : Wr2; T = (v < 32768) ? T2l : T2r;
    } else {                          // layer3: 128x64
        int v = id - 131072; if (v >= 2 * 8192) return;
        K = 128; No = 64; idx = v & 8191;
        W = (v < 8192) ? Wl3 : Wr3; T = (v < 8192) ? T3l : T3r;
    }
    int n = idx / K, k = idx - n * K;
    T[idx] = f2bf(W[(size_t)k * No + n]);
}

// ---------------- MFMA GEMM ------------------------------------------------
// z=0: A*W0 + bias0 -> Cb (bf16);  z=1: A*W1 + bias1 -> Cf (f32)
__global__ __launch_bounds__(256) void gemm_mfma(
    const unsigned short* __restrict__ A,     // [M][K] bf16
    const unsigned short* __restrict__ W0, const unsigned short* __restrict__ W1,
    const float* __restrict__ bias0, const float* __restrict__ bias1,
    unsigned short* __restrict__ Cb, float* __restrict__ Cf,
    int M, int No, int K)
{
    const unsigned short* Wt = blockIdx.z ? W1 : W0;  // [No][K] bf16
    const float* bias = blockIdx.z ? bias1 : bias0;

    __shared__ __align__(16) char smem[128 * 64 * 2 + 64 * 64 * 2];
    char* As = smem;
    char* Bs = smem + 16384;

    const int t = threadIdx.x;
    const int lane = t & 63;
    const int wid = t >> 6;
    const int wm = wid >> 1, wn = wid & 1;
    const int row0 = blockIdx.x * 128;
    const int col0 = blockIdx.y * 64;
    const int nk = K >> 6;

    f32x4 acc[4][2];
    #pragma unroll
    for (int i = 0; i < 4; ++i)
        #pragma unroll
        for (int j = 0; j < 2; ++j)
            acc[i][j] = (f32x4){0.f, 0.f, 0.f, 0.f};

    uint4 stA[4]; uint4 stB[2];
    {
        #pragma unroll
        for (int i = 0; i < 4; ++i) {
            int c16 = t * 4 + i; int r = c16 >> 3, j = c16 & 7;
            int gr = row0 + r; if (gr > M - 1) gr = M - 1;
            stA[i] = *reinterpret_cast<const uint4*>(A + (size_t)gr * K + j * 8);
        }
        #pragma unroll
        for (int i = 0; i < 2; ++i) {
            int c16 = t * 2 + i; int n = c16 >> 3, j = c16 & 7;
            stB[i] = *reinterpret_cast<const uint4*>(Wt + (size_t)(col0 + n) * K + j * 8);
        }
    }

    for (int kt = 0; kt < nk; ++kt) {
        #pragma unroll
        for (int i = 0; i < 4; ++i) {
            int c16 = t * 4 + i; int r = c16 >> 3, j = c16 & 7;
            *reinterpret_cast<uint4*>(As + r * 128 + ((j ^ (r & 7)) << 4)) = stA[i];
        }
        #pragma unroll
        for (int i = 0; i < 2; ++i) {
            int c16 = t * 2 + i; int n = c16 >> 3, j = c16 & 7;
            *reinterpret_cast<uint4*>(Bs + n * 128 + ((j ^ (n & 7)) << 4)) = stB[i];
        }
        __syncthreads();
        if (kt + 1 < nk) {
            int ko = (kt + 1) * 64;
            #pragma unroll
            for (int i = 0; i < 4; ++i) {
                int c16 = t * 4 + i; int r = c16 >> 3, j = c16 & 7;
                int gr = row0 + r; if (gr > M - 1) gr = M - 1;
                stA[i] = *reinterpret_cast<const uint4*>(A + (size_t)gr * K + ko + j * 8);
            }
            #pragma unroll
            for (int i = 0; i < 2; ++i) {
                int c16 = t * 2 + i; int n = c16 >> 3, j = c16 & 7;
                stB[i] = *reinterpret_cast<const uint4*>(Wt + (size_t)(col0 + n) * K + ko + j * 8);
            }
        }
        #pragma unroll
        for (int kk = 0; kk < 2; ++kk) {
            bf16x8 a[4], b[2];
            const int kb2 = (kk * 32 + (lane >> 4) * 8) * 2;
            #pragma unroll
            for (int i = 0; i < 4; ++i) {
                int r = wm * 64 + i * 16 + (lane & 15);
                a[i] = *reinterpret_cast<const bf16x8*>(As + r * 128 + (kb2 ^ ((r & 7) << 4)));
            }
            #pragma unroll
            for (int j = 0; j < 2; ++j) {
                int n = wn * 32 + j * 16 + (lane & 15);
                b[j] = *reinterpret_cast<const bf16x8*>(Bs + n * 128 + (kb2 ^ ((n & 7) << 4)));
            }
            #pragma unroll
            for (int i = 0; i < 4; ++i)
                #pragma unroll
                for (int j = 0; j < 2; ++j)
                    acc[i][j] = __builtin_amdgcn_mfma_f32_16x16x32_bf16(a[i], b[j], acc[i][j], 0, 0, 0);
        }
        __syncthreads();
    }

    const bool isB = (blockIdx.z == 0);
    #pragma unroll
    for (int j = 0; j < 2; ++j) {
        int c = col0 + wn * 32 + j * 16 + (lane & 15);
        float bb = bias[c];
        #pragma unroll
        for (int i = 0; i < 4; ++i) {
            #pragma unroll
            for (int q = 0; q < 4; ++q) {
                int r = row0 + wm * 64 + i * 16 + (lane >> 4) * 4 + q;
                if (r < M) {
                    float v = acc[i][j][q] + bb;
                    if (isB) Cb[(size_t)r * No + c] = f2bf(v);
                    else     Cf[(size_t)r * No + c] = v;
                }
            }
        }
    }
}

// ---------------- CSR build ------------------------------------------------
__global__ void hist_kernel(const int* __restrict__ ei, int E, int Etot,
                            int* __restrict__ deg)
{
    int i = blockIdx.x * blockDim.x + threadIdx.x;
    if (i >= Etot) return;
    int d = (i < E) ? ei[E + i] : (i - E);
    atomicAdd(&deg[d], 1);
}

// ---- 3-phase coalesced scan of deg[0..N) -> rowptr/cursor ----------------
__global__ __launch_bounds__(256) void scan1_kernel(
    const int* __restrict__ deg, int* __restrict__ blockSums, int N)
{
    __shared__ int red[256];
    const int b = blockIdx.x, t = threadIdx.x;
    const int chunk = (N + SCAN_BLOCKS - 1) / SCAN_BLOCKS;
    const int lo = b * chunk;
    const int hi = (lo + chunk < N) ? lo + chunk : N;
    int s = 0;
    for (int i = lo + t; i < hi; i += 256) s += deg[i];
    red[t] = s;
    __syncthreads();
    #pragma unroll
    for (int off = 128; off > 0; off >>= 1) {
        if (t < off) red[t] += red[t + off];
        __syncthreads();
    }
    if (t == 0) blockSums[b] = red[0];
}

__global__ __launch_bounds__(256) void scan2_kernel(
    const int* __restrict__ blockSums, int* __restrict__ blockBase,
    int* __restrict__ rowptr, int N)
{
    __shared__ int tmp[256];
    const int t = threadIdx.x;
    int v = blockSums[t];
    tmp[t] = v;
    __syncthreads();
    for (int off = 1; off < 256; off <<= 1) {
        int u = (t >= off) ? tmp[t - off] : 0;
        __syncthreads();
        tmp[t] += u;
        __syncthreads();
    }
    blockBase[t] = tmp[t] - v;        // exclusive
    if (t == 255) rowptr[N] = tmp[255];
}

__global__ __launch_bounds__(256) void scan3_kernel(
    const int* __restrict__ deg, const int* __restrict__ blockBase,
    int* __restrict__ rowptr, int* __restrict__ cursor, int N)
{
    __shared__ int tmp[256];
    __shared__ int carry;
    const int b = blockIdx.x, t = threadIdx.x;
    const int chunk = (N + SCAN_BLOCKS - 1) / SCAN_BLOCKS;
    const int lo = b * chunk;
    const int hi = (lo + chunk < N) ? lo + chunk : N;
    if (t == 0) carry = blockBase[b];
    __syncthreads();
    for (int j = lo; j < hi; j += 256) {
        int i = j + t;
        int v = (i < hi) ? deg[i] : 0;
        tmp[t] = v;
        __syncthreads();
        for (int off = 1; off < 256; off <<= 1) {
            int u = (t >= off) ? tmp[t - off] : 0;
            __syncthreads();
            tmp[t] += u;
            __syncthreads();
        }
        int excl = carry + tmp[t] - v;
        if (i < hi) { rowptr[i] = excl; cursor[i] = excl; }
        __syncthreads();
        if (t == 255) carry += tmp[255];
        __syncthreads();
    }
}

__global__ void scatter_kernel(const int* __restrict__ ei, int E, int Etot,
                               int* __restrict__ cursor, int* __restrict__ ssrc)
{
    int i = blockIdx.x * blockDim.x + threadIdx.x;
    if (i >= Etot) return;
    int d, s;
    if (i < E) { s = ei[i]; d = ei[E + i]; }
    else       { s = i - E; d = s; }
    int pos = atomicAdd(&cursor[d], 1);
    ssrc[pos] = s;
}

// ---------------- degree sort, contention-free ----------------------------
__global__ __launch_bounds__(256) void dhist2_kernel(
    const int* __restrict__ rowptr, int* __restrict__ blockHist, int N)
{
    __shared__ int lh[256];
    lh[threadIdx.x] = 0;
    __syncthreads();
    const int chunk = (N + SORT_BLOCKS - 1) / SORT_BLOCKS;
    const int lo = blockIdx.x * chunk;
    const int hi = (lo + chunk < N) ? lo + chunk : N;
    for (int d = lo + threadIdx.x; d < hi; d += 256) {
        int deg = rowptr[d + 1] - rowptr[d];
        atomicAdd(&lh[deg > 255 ? 255 : deg], 1);
    }
    __syncthreads();
    blockHist[blockIdx.x * 256 + threadIdx.x] = lh[threadIdx.x];
}

__global__ __launch_bounds__(256) void dscan2_kernel(
    const int* __restrict__ blockHist, int* __restrict__ blockOff)
{
    const int t = threadIdx.x;          // t = bin
    int total = 0;
    for (int b = 0; b < SORT_BLOCKS; ++b) total += blockHist[b * 256 + t];
    __shared__ int tmp[256];
    tmp[t] = total;
    __syncthreads();
    for (int off = 1; off < 256; off <<= 1) {
        int v = (t >= off) ? tmp[t - off] : 0;
        __syncthreads();
        tmp[t] += v;
        __syncthreads();
    }
    int start = (t == 0) ? 0 : tmp[t - 1];
    for (int b = 0; b < SORT_BLOCKS; ++b) {
        blockOff[b * 256 + t] = start;
        start += blockHist[b * 256 + t];
    }
}

__global__ __launch_bounds__(256) void dscatter2_kernel(
    const int* __restrict__ rowptr, const int* __restrict__ blockOff,
    int* __restrict__ dperm, int N)
{
    __shared__ int cur[256];
    cur[threadIdx.x] = blockOff[blockIdx.x * 256 + threadIdx.x];
    __syncthreads();
    const int chunk = (N + SORT_BLOCKS - 1) / SORT_BLOCKS;
    const int lo = blockIdx.x * chunk;
    const int hi = (lo + chunk < N) ? lo + chunk : N;
    for (int d = lo + threadIdx.x; d < hi; d += 256) {
        int deg = rowptr[d + 1] - rowptr[d];
        int pos = atomicAdd(&cur[deg > 255 ? 255 : deg], 1);
        dperm[pos] = d;
    }
}

// ---------------- fused edge kernel: 4-lane group per (dst, head) ---------
template <int H, bool OUT_F32, bool OUT_BF16>
__global__ __launch_bounds__(256) void gat_fused4(
    const int* __restrict__ rowptr, const int* __restrict__ ssrc,
    const int* __restrict__ dperm,
    const unsigned short* __restrict__ xl, const float* __restrict__ xr,
    const float* __restrict__ att, const float* __restrict__ bias,
    float* __restrict__ outf, unsigned short* __restrict__ outb, int N)
{
    const int gid = blockIdx.x * 64 + (threadIdx.x >> 2);
    const int sub = threadIdx.x & 3;
    if (gid >= N * H) return;
    const int di = gid / H;
    const int h  = gid - di * H;
    const int d  = dperm[di];
    const int HC = H * 64;
    const int co = h * 64 + sub * 16;

    float xrv[16], attv[16], acc[16];
    {
        const float* pr = xr + (size_t)d * HC + co;
        const float* pa = att + co;
        #pragma unroll
        for (int k = 0; k < 16; k += 4) {
            float4 v = *reinterpret_cast<const float4*>(pr + k);
            xrv[k] = v.x; xrv[k+1] = v.y; xrv[k+2] = v.z; xrv[k+3] = v.w;
            float4 w = *reinterpret_cast<const float4*>(pa + k);
            attv[k] = w.x; attv[k+1] = w.y; attv[k+2] = w.z; attv[k+3] = w.w;
        }
    }
    #pragma unroll
    for (int k = 0; k < 16; ++k) acc[k] = 0.f;
    float M = -3.0e38f, S = 0.f;

    const int begin = rowptr[d], end = rowptr[d + 1];
    uint4 c0, c1;
    {
        const unsigned short* pl = xl + (size_t)ssrc[begin] * HC + co;
        c0 = *reinterpret_cast<const uint4*>(pl);
        c1 = *reinterpret_cast<const uint4*>(pl + 8);
    }
    for (int e = begin; e < end; ++e) {
        uint4 n0, n1;
        const bool more = (e + 1 < end);
        if (more) {
            const unsigned short* pl = xl + (size_t)ssrc[e + 1] * HC + co;
            n0 = *reinterpret_cast<const uint4*>(pl);
            n1 = *reinterpret_cast<const uint4*>(pl + 8);
        }
        float cur[16];
        unpack8(c0, cur);
        unpack8(c1, cur + 8);
        float p = 0.f;
        #pragma unroll
        for (int k = 0; k < 16; ++k) {
            float v = cur[k] + xrv[k];
            v = fmaxf(v, 0.2f * v);
            p = fmaf(v, attv[k], p);
        }
        p += __shfl_xor(p, 1);
        p += __shfl_xor(p, 2);
        float nM = fmaxf(M, p);
        float scale = __expf(M - nM);
        float w = __expf(p - nM);
        S = fmaf(S, scale, w);
        #pragma unroll
        for (int k = 0; k < 16; ++k) acc[k] = fmaf(acc[k], scale, w * cur[k]);
        M = nM;
        if (more) { c0 = n0; c1 = n1; }
    }
    float inv = 1.f / S;
    const float* pb = bias + co;
    #pragma unroll
    for (int k = 0; k < 16; ++k) {
        float val = fmaf(acc[k], inv, pb[k]);
        acc[k] = val > 0.f ? val : 0.f;
    }
    size_t ob = (size_t)d * HC + co;
    if (OUT_F32) {
        #pragma unroll
        for (int k = 0; k < 16; k += 4) {
            float4 v = {acc[k], acc[k+1], acc[k+2], acc[k+3]};
            *reinterpret_cast<float4*>(outf + ob + k) = v;
        }
    }
    if (OUT_BF16) {
        unsigned pk[8];
        #pragma unroll
        for (int k = 0; k < 8; ++k)
            pk[k] = (unsigned)f2bf(acc[2*k]) | ((unsigned)f2bf(acc[2*k+1]) << 16);
        uint4 lo = {pk[0], pk[1], pk[2], pk[3]};
        uint4 hi = {pk[4], pk[5], pk[6], pk[7]};
        *reinterpret_cast<uint4*>(outb + ob) = lo;
        *reinterpret_cast<uint4*>(outb + ob + 8) = hi;
    }
}

// ---------------- segmented pool (batch sorted) + counts ------------------
__global__ __launch_bounds__(256) void pool_kernel2(
    const float* __restrict__ h3, const int* __restrict__ batch,
    float* __restrict__ sums, float* __restrict__ counts, int N)
{
    const int wave = blockIdx.x * 4 + (threadIdx.x >> 6);
    const int lane = threadIdx.x & 63;
    const int n0 = wave * 64;
    if (n0 >= N) return;
    const int n1 = (n0 + 64 < N) ? n0 + 64 : N;
    float s = 0.f, cnt = 0.f;
    int g = batch[n0];
    for (int n = n0; n < n1; ++n) {
        int gn = batch[n];
        if (gn != g) {
            atomicAdd(&sums[g * 64 + lane], s);
            if (lane == 0) atomicAdd(&counts[g], cnt);
            s = 0.f; cnt = 0.f; g = gn;
        }
        s += h3[(size_t)n * 64 + lane];
        cnt += 1.f;
    }
    atomicAdd(&sums[g * 64 + lane], s);
    if (lane == 0) atomicAdd(&counts[g], cnt);
}

// ---------------- MLP ------------------------------------------------------
__global__ __launch_bounds__(64) void mlp_kernel(
    const float* __restrict__ sums, const float* __restrict__ counts,
    const float* __restrict__ Wm1, const float* __restrict__ bm1,
    const float* __restrict__ Wm2, const float* __restrict__ bm2,
    float* __restrict__ out)
{
    int g = blockIdx.x;
    int t = threadIdx.x;
    __shared__ float pooled[64];
    __shared__ float hidden[32];
    float cnt = counts[g];
    cnt = cnt > 1.f ? cnt : 1.f;
    pooled[t] = sums[g * 64 + t] / cnt;
    __syncthreads();
    if (t < 32) {
        float a = bm1[t];
        #pragma unroll
        for (int k = 0; k < 64; ++k) a = fmaf(pooled[k], Wm1[k * 32 + t], a);
        hidden[t] = a > 0.f ? a : 0.f;
    }
    __syncthreads();
    if (t < 2) {
        float a = bm2[t];
        #pragma unroll
        for (int j = 0; j < 32; ++j) a = fmaf(hidden[j], Wm2[j * 2 + t], a);
        out[g * 2 + t] = a;
    }
}

// ---------------- layer driver ---------------------------------------------
static void run_layer(const unsigned short* Xb, int K, int H,
                      const float* bl, const float* br,
                      const float* att, const float* bias_out,
                      const unsigned short* Wtl, const unsigned short* Wtr,
                      const int* rowptr, const int* ssrc, const int* dperm, int N,
                      unsigned short* xl, float* xr,
                      float* houtf, unsigned short* houtb,
                      hipStream_t stream)
{
    const int No = H * 64;
    dim3 g((N + 127) / 128, No / 64, 2);
    gemm_mfma<<<g, 256, 0, stream>>>(Xb, Wtl, Wtr, bl, br, xl, xr, N, No, K);

    int ngroups = N * H;
    int blocks = (ngroups + 63) / 64;
    if (H == 4)
        gat_fused4<4, false, true><<<blocks, 256, 0, stream>>>(
            rowptr, ssrc, dperm, xl, xr, att, bias_out, houtf, houtb, N);
    else if (H == 2)
        gat_fused4<2, false, true><<<blocks, 256, 0, stream>>>(
            rowptr, ssrc, dperm, xl, xr, att, bias_out, houtf, houtb, N);
    else
        gat_fused4<1, true, false><<<blocks, 256, 0, stream>>>(
            rowptr, ssrc, dperm, xl, xr, att, bias_out, houtf, houtb, N);
}

extern "C" void kernel_launch(void* const* d_in, const int* in_sizes, int n_in,
                              void* d_out, int out_size, void* d_ws, size_t ws_size,
                              hipStream_t stream)
{
    const float* x    = (const float*)d_in[0];
    const int*   ei   = (const int*)d_in[1];
    const int*   batch= (const int*)d_in[2];
    const float* Wl1 = (const float*)d_in[3];
    const float* bl1 = (const float*)d_in[4];
    const float* Wr1 = (const float*)d_in[5];
    const float* br1 = (const float*)d_in[6];
    const float* att1= (const float*)d_in[7];
    const float* b1  = (const float*)d_in[8];
    const float* Wl2 = (const float*)d_in[9];
    const float* bl2 = (const float*)d_in[10];
    const float* Wr2 = (const float*)d_in[11];
    const float* br2 = (const float*)d_in[12];
    const float* att2= (const float*)d_in[13];
    const float* b2  = (const float*)d_in[14];
    const float* Wl3 = (const float*)d_in[15];
    const float* bl3 = (const float*)d_in[16];
    const float* Wr3 = (const float*)d_in[17];
    const float* br3 = (const float*)d_in[18];
    const float* att3= (const float*)d_in[19];
    const float* b3  = (const float*)d_in[20];
    const float* Wm1 = (const float*)d_in[21];
    const float* bm1 = (const float*)d_in[22];
    const float* Wm2 = (const float*)d_in[23];
    const float* bm2 = (const float*)d_in[24];

    const int N    = in_sizes[2];          // 50000
    const int E    = in_sizes[1] / 2;      // 800000
    const int Etot = E + N;                // + self loops
    const int K1   = in_sizes[0] / N;      // 128

    // workspace layout
    char* wsb = (char*)d_ws;
    size_t o = 0;
    auto alloc = [&](size_t bytes) { char* p = wsb + o; o += (bytes + 255) & ~(size_t)255; return p; };
    unsigned short* xl    = (unsigned short*)alloc((size_t)N * 256 * 2);
    float*          xr    = (float*)alloc((size_t)N * 256 * 4);
    unsigned short* xb    = (unsigned short*)alloc((size_t)N * K1 * 2);
    unsigned short* h1b   = (unsigned short*)alloc((size_t)N * 256 * 2);
    unsigned short* h2b   = (unsigned short*)alloc((size_t)N * 128 * 2);
    float*          h3f   = (float*)alloc((size_t)N * 64 * 4);
    int*   deg    = (int*)alloc((size_t)N * 4);
    int*   rowptr = (int*)alloc((size_t)(N + 1) * 4);
    int*   cursor = (int*)alloc((size_t)N * 4);
    int*   ssrc   = (int*)alloc((size_t)Etot * 4);
    int*   dperm  = (int*)alloc((size_t)N * 4);
    int*   blockHist = (int*)alloc((size_t)SORT_BLOCKS * 256 * 4);
    int*   blockOff  = (int*)alloc((size_t)SORT_BLOCKS * 256 * 4);
    int*   blockSums = (int*)alloc((size_t)SCAN_BLOCKS * 4);
    int*   blockBase = (int*)alloc((size_t)SCAN_BLOCKS * 4);
    unsigned short* Wt1l = (unsigned short*)alloc(128 * 256 * 2);
    unsigned short* Wt1r = (unsigned short*)alloc(128 * 256 * 2);
    unsigned short* Wt2l = (unsigned short*)alloc(256 * 128 * 2);
    unsigned short* Wt2r = (unsigned short*)alloc(256 * 128 * 2);
    unsigned short* Wt3l = (unsigned short*)alloc(128 * 64 * 2);
    unsigned short* Wt3r = (unsigned short*)alloc(128 * 64 * 2);
    float* sums   = (float*)alloc(64 * 64 * 4);
    float* counts = (float*)alloc(64 * 4);
    (void)ws_size; (void)n_in; (void)out_size;

    // ---- CSR build + degree sort (shared by all 3 layers) ----
    hipMemsetAsync(deg, 0, (size_t)N * 4, stream);
    hist_kernel<<<(Etot + 255) / 256, 256, 0, stream>>>(ei, E, Etot, deg);
    scan1_kernel<<<SCAN_BLOCKS, 256, 0, stream>>>(deg, blockSums, N);
    scan2_kernel<<<1, 256, 0, stream>>>(blockSums, blockBase, rowptr, N);
    scan3_kernel<<<SCAN_BLOCKS, 256, 0, stream>>>(deg, blockBase, rowptr, cursor, N);
    scatter_kernel<<<(Etot + 255) / 256, 256, 0, stream>>>(ei, E, Etot, cursor, ssrc);
    dhist2_kernel<<<SORT_BLOCKS, 256, 0, stream>>>(rowptr, blockHist, N);
    dscan2_kernel<<<1, 256, 0, stream>>>(blockHist, blockOff);
    dscatter2_kernel<<<SORT_BLOCKS, 256, 0, stream>>>(rowptr, blockOff, dperm, N);

    // ---- convert input x + all weights to bf16 ----
    cvt_kernel<<<((N * K1) / 4 + 255) / 256, 256, 0, stream>>>(x, xb, N * K1);
    cvt_wt_all_kernel<<<(147456 + 255) / 256, 256, 0, stream>>>(
        Wl1, Wr1, Wt1l, Wt1r, Wl2, Wr2, Wt2l, Wt2r, Wl3, Wr3, Wt3l, Wt3r);

    // ---- layers ----
    run_layer(xb, K1, 4, bl1, br1, att1, b1, Wt1l, Wt1r,
              rowptr, ssrc, dperm, N, xl, xr, nullptr, h1b, stream);
    run_layer(h1b, 256, 2, bl2, br2, att2, b2, Wt2l, Wt2r,
              rowptr, ssrc, dperm, N, xl, xr, nullptr, h2b, stream);
    run_layer(h2b, 128, 1, bl3, br3, att3, b3, Wt3l, Wt3r,
              rowptr, ssrc, dperm, N, xl, xr, h3f, nullptr, stream);

    // ---- pool + MLP ----
    hipMemsetAsync(sums, 0, 64 * 64 * 4, stream);
    hipMemsetAsync(counts, 0, 64 * 4, stream);
    {
        int waves = (N + 63) / 64;
        pool_kernel2<<<(waves + 3) / 4, 256, 0, stream>>>(h3f, batch, sums, counts, N);
    }
    mlp_kernel<<<64, 64, 0, stream>>>(sums, counts, Wm1, bm1, Wm2, bm2, (float*)d_out);
}

// Round 7
// 469.876 us; speedup vs baseline: 6.0881x; 1.0516x over previous
//
#include <hip/hip_runtime.h>

// GATv2 GNN classifier.
// R7: head-major xl/xr layout ([h][N][64]) + head-major group ordering in the
// edge kernel -> per-phase gather working set drops from 25.6MB to 6.4MB
// (L2-resident per XCD). Degree-DESCENDING schedule (suffix-sum) for tail
// overlap. Rest: bf16 MFMA GEMMs, bf16 xl gather, contention-free sort/scan.

typedef __attribute__((ext_vector_type(8))) short bf16x8;
typedef __attribute__((ext_vector_type(4))) float f32x4;

#define SORT_BLOCKS 64
#define SCAN_BLOCKS 256

__device__ inline unsigned short f2bf(float f) {
    unsigned u = __float_as_uint(f);
    unsigned r = (u + 0x7fff + ((u >> 16) & 1)) >> 16;   // RNE
    return (unsigned short)r;
}

__device__ inline void unpack8(uint4 a, float* d) {
    d[0] = __uint_as_float(a.x << 16); d[1] = __uint_as_float(a.x & 0xffff0000u);
    d[2] = __uint_as_float(a.y << 16); d[3] = __uint_as_float(a.y & 0xffff0000u);
    d[4] = __uint_as_float(a.z << 16); d[5] = __uint_as_float(a.z & 0xffff0000u);
    d[6] = __uint_as_float(a.w << 16); d[7] = __uint_as_float(a.w & 0xffff0000u);
}

// ---------------- fp32 -> bf16 elementwise convert ------------------------
__global__ void cvt_kernel(const float* __restrict__ in,
                           unsigned short* __restrict__ out, int n)
{
    int i = (blockIdx.x * blockDim.x + threadIdx.x) * 4;
    if (i >= n) return;
    float4 v = *reinterpret_cast<const float4*>(in + i);
    ushort4 o;
    o.x = f2bf(v.x); o.y = f2bf(v.y); o.z = f2bf(v.z); o.w = f2bf(v.w);
    *reinterpret_cast<ushort4*>(out + i) = o;
}

// ---------------- all six W [K][No] fp32 -> Wt [No][K] bf16, one launch ----
__global__ void cvt_wt_all_kernel(
    const float* __restrict__ Wl1, const float* __restrict__ Wr1, unsigned short* __restrict__ T1l, unsigned short* __restrict__ T1r,
    const float* __restrict__ Wl2, const float* __restrict__ Wr2, unsigned short* __restrict__ T2l, unsigned short* __restrict__ T2r,
    const float* __restrict__ Wl3, const float* __restrict__ Wr3, unsigned short* __restrict__ T3l, unsigned short* __restrict__ T3r)
{
    int id = blockIdx.x * blockDim.x + threadIdx.x;
    const float* W; unsigned short* T; int K, No, idx;
    if (id < 2 * 32768) {            // layer1: 128x256
        K = 128; No = 256; idx = id & 32767;
        W = (id < 32768) ? Wl1 : Wr1; T = (id < 32768) ? T1l : T1r;
    } else if (id < 2 * 32768 + 2 * 32768) {  // layer2: 256x128
        int v = id - 65536; K = 256; No = 128; idx = v & 32767;
        W = (v < 32768) ? Wl2 : Wr2; T = (v < 32768) ? T2l : T2r;
    } else {                          // layer3: 128x64
        int v = id - 131072; if (v >= 2 * 8192) return;
        K = 128; No = 64; idx = v & 8191;
        W = (v < 8192) ? Wl3 : Wr3; T = (v < 8192) ? T3l : T3r;
    }
    int n = idx / K, k = idx - n * K;
    T[idx] = f2bf(W[(size_t)k * No + n]);
}

// ---------------- MFMA GEMM ------------------------------------------------
// z=0: A*W0+bias0 -> Cb bf16, HEAD-MAJOR [h][M][64]
// z=1: A*W1+bias1 -> Cf f32,  HEAD-MAJOR [h][M][64]
__global__ __launch_bounds__(256) void gemm_mfma(
    const unsigned short* __restrict__ A,     // [M][K] bf16
    const unsigned short* __restrict__ W0, const unsigned short* __restrict__ W1,
    const float* __restrict__ bias0, const float* __restrict__ bias1,
    unsigned short* __restrict__ Cb, float* __restrict__ Cf,
    int M, int No, int K)
{
    const unsigned short* Wt = blockIdx.z ? W1 : W0;  // [No][K] bf16
    const float* bias = blockIdx.z ? bias1 : bias0;

    __shared__ __align__(16) char smem[128 * 64 * 2 + 64 * 64 * 2];
    char* As = smem;
    char* Bs = smem + 16384;

    const int t = threadIdx.x;
    const int lane = t & 63;
    const int wid = t >> 6;
    const int wm = wid >> 1, wn = wid & 1;
    const int row0 = blockIdx.x * 128;
    const int col0 = blockIdx.y * 64;
    const int nk = K >> 6;

    f32x4 acc[4][2];
    #pragma unroll
    for (int i = 0; i < 4; ++i)
        #pragma unroll
        for (int j = 0; j < 2; ++j)
            acc[i][j] = (f32x4){0.f, 0.f, 0.f, 0.f};

    uint4 stA[4]; uint4 stB[2];
    {
        #pragma unroll
        for (int i = 0; i < 4; ++i) {
            int c16 = t * 4 + i; int r = c16 >> 3, j = c16 & 7;
            int gr = row0 + r; if (gr > M - 1) gr = M - 1;
            stA[i] = *reinterpret_cast<const uint4*>(A + (size_t)gr * K + j * 8);
        }
        #pragma unroll
        for (int i = 0; i < 2; ++i) {
            int c16 = t * 2 + i; int n = c16 >> 3, j = c16 & 7;
            stB[i] = *reinterpret_cast<const uint4*>(Wt + (size_t)(col0 + n) * K + j * 8);
        }
    }

    for (int kt = 0; kt < nk; ++kt) {
        #pragma unroll
        for (int i = 0; i < 4; ++i) {
            int c16 = t * 4 + i; int r = c16 >> 3, j = c16 & 7;
            *reinterpret_cast<uint4*>(As + r * 128 + ((j ^ (r & 7)) << 4)) = stA[i];
        }
        #pragma unroll
        for (int i = 0; i < 2; ++i) {
            int c16 = t * 2 + i; int n = c16 >> 3, j = c16 & 7;
            *reinterpret_cast<uint4*>(Bs + n * 128 + ((j ^ (n & 7)) << 4)) = stB[i];
        }
        __syncthreads();
        if (kt + 1 < nk) {
            int ko = (kt + 1) * 64;
            #pragma unroll
            for (int i = 0; i < 4; ++i) {
                int c16 = t * 4 + i; int r = c16 >> 3, j = c16 & 7;
                int gr = row0 + r; if (gr > M - 1) gr = M - 1;
                stA[i] = *reinterpret_cast<const uint4*>(A + (size_t)gr * K + ko + j * 8);
            }
            #pragma unroll
            for (int i = 0; i < 2; ++i) {
                int c16 = t * 2 + i; int n = c16 >> 3, j = c16 & 7;
                stB[i] = *reinterpret_cast<const uint4*>(Wt + (size_t)(col0 + n) * K + ko + j * 8);
            }
        }
        #pragma unroll
        for (int kk = 0; kk < 2; ++kk) {
            bf16x8 a[4], b[2];
            const int kb2 = (kk * 32 + (lane >> 4) * 8) * 2;
            #pragma unroll
            for (int i = 0; i < 4; ++i) {
                int r = wm * 64 + i * 16 + (lane & 15);
                a[i] = *reinterpret_cast<const bf16x8*>(As + r * 128 + (kb2 ^ ((r & 7) << 4)));
            }
            #pragma unroll
            for (int j = 0; j < 2; ++j) {
                int n = wn * 32 + j * 16 + (lane & 15);
                b[j] = *reinterpret_cast<const bf16x8*>(Bs + n * 128 + (kb2 ^ ((n & 7) << 4)));
            }
            #pragma unroll
            for (int i = 0; i < 4; ++i)
                #pragma unroll
                for (int j = 0; j < 2; ++j)
                    acc[i][j] = __builtin_amdgcn_mfma_f32_16x16x32_bf16(a[i], b[j], acc[i][j], 0, 0, 0);
        }
        __syncthreads();
    }

    const bool isB = (blockIdx.z == 0);
    #pragma unroll
    for (int j = 0; j < 2; ++j) {
        int c = col0 + wn * 32 + j * 16 + (lane & 15);
        float bb = bias[c];
        const size_t hb = (size_t)(c >> 6) * M;   // head-major base
        const int cc = c & 63;
        #pragma unroll
        for (int i = 0; i < 4; ++i) {
            #pragma unroll
            for (int q = 0; q < 4; ++q) {
                int r = row0 + wm * 64 + i * 16 + (lane >> 4) * 4 + q;
                if (r < M) {
                    float v = acc[i][j][q] + bb;
                    if (isB) Cb[(hb + r) * 64 + cc] = f2bf(v);
                    else     Cf[(hb + r) * 64 + cc] = v;
                }
            }
        }
    }
}

// ---------------- CSR build ------------------------------------------------
__global__ void hist_kernel(const int* __restrict__ ei, int E, int Etot,
                            int* __restrict__ deg)
{
    int i = blockIdx.x * blockDim.x + threadIdx.x;
    if (i >= Etot) return;
    int d = (i < E) ? ei[E + i] : (i - E);
    atomicAdd(&deg[d], 1);
}

// ---- 3-phase coalesced scan of deg[0..N) -> rowptr/cursor ----------------
__global__ __launch_bounds__(256) void scan1_kernel(
    const int* __restrict__ deg, int* __restrict__ blockSums, int N)
{
    __shared__ int red[256];
    const int b = blockIdx.x, t = threadIdx.x;
    const int chunk = (N + SCAN_BLOCKS - 1) / SCAN_BLOCKS;
    const int lo = b * chunk;
    const int hi = (lo + chunk < N) ? lo + chunk : N;
    int s = 0;
    for (int i = lo + t; i < hi; i += 256) s += deg[i];
    red[t] = s;
    __syncthreads();
    #pragma unroll
    for (int off = 128; off > 0; off >>= 1) {
        if (t < off) red[t] += red[t + off];
        __syncthreads();
    }
    if (t == 0) blockSums[b] = red[0];
}

__global__ __launch_bounds__(256) void scan2_kernel(
    const int* __restrict__ blockSums, int* __restrict__ blockBase,
    int* __restrict__ rowptr, int N)
{
    __shared__ int tmp[256];
    const int t = threadIdx.x;
    int v = blockSums[t];
    tmp[t] = v;
    __syncthreads();
    for (int off = 1; off < 256; off <<= 1) {
        int u = (t >= off) ? tmp[t - off] : 0;
        __syncthreads();
        tmp[t] += u;
        __syncthreads();
    }
    blockBase[t] = tmp[t] - v;        // exclusive
    if (t == 255) rowptr[N] = tmp[255];
}

__global__ __launch_bounds__(256) void scan3_kernel(
    const int* __restrict__ deg, const int* __restrict__ blockBase,
    int* __restrict__ rowptr, int* __restrict__ cursor, int N)
{
    __shared__ int tmp[256];
    __shared__ int carry;
    const int b = blockIdx.x, t = threadIdx.x;
    const int chunk = (N + SCAN_BLOCKS - 1) / SCAN_BLOCKS;
    const int lo = b * chunk;
    const int hi = (lo + chunk < N) ? lo + chunk : N;
    if (t == 0) carry = blockBase[b];
    __syncthreads();
    for (int j = lo; j < hi; j += 256) {
        int i = j + t;
        int v = (i < hi) ? deg[i] : 0;
        tmp[t] = v;
        __syncthreads();
        for (int off = 1; off < 256; off <<= 1) {
            int u = (t >= off) ? tmp[t - off] : 0;
            __syncthreads();
            tmp[t] += u;
            __syncthreads();
        }
        int excl = carry + tmp[t] - v;
        if (i < hi) { rowptr[i] = excl; cursor[i] = excl; }
        __syncthreads();
        if (t == 255) carry += tmp[255];
        __syncthreads();
    }
}

__global__ void scatter_kernel(const int* __restrict__ ei, int E, int Etot,
                               int* __restrict__ cursor, int* __restrict__ ssrc)
{
    int i = blockIdx.x * blockDim.x + threadIdx.x;
    if (i >= Etot) return;
    int d, s;
    if (i < E) { s = ei[i]; d = ei[E + i]; }
    else       { s = i - E; d = s; }
    int pos = atomicAdd(&cursor[d], 1);
    ssrc[pos] = s;
}

// ---------------- degree sort (DESCENDING), contention-free ---------------
__global__ __launch_bounds__(256) void dhist2_kernel(
    const int* __restrict__ rowptr, int* __restrict__ blockHist, int N)
{
    __shared__ int lh[256];
    lh[threadIdx.x] = 0;
    __syncthreads();
    const int chunk = (N + SORT_BLOCKS - 1) / SORT_BLOCKS;
    const int lo = blockIdx.x * chunk;
    const int hi = (lo + chunk < N) ? lo + chunk : N;
    for (int d = lo + threadIdx.x; d < hi; d += 256) {
        int deg = rowptr[d + 1] - rowptr[d];
        atomicAdd(&lh[deg > 255 ? 255 : deg], 1);
    }
    __syncthreads();
    blockHist[blockIdx.x * 256 + threadIdx.x] = lh[threadIdx.x];
}

__global__ __launch_bounds__(256) void dscan2_kernel(
    const int* __restrict__ blockHist, int* __restrict__ blockOff)
{
    const int t = threadIdx.x;          // t = bin
    int total = 0;
    for (int b = 0; b < SORT_BLOCKS; ++b) total += blockHist[b * 256 + t];
    __shared__ int tmp[256];
    tmp[t] = total;
    __syncthreads();
    for (int off = 1; off < 256; off <<= 1) {
        int v = (t >= off) ? tmp[t - off] : 0;
        __syncthreads();
        tmp[t] += v;
        __syncthreads();
    }
    // descending: bin t starts after all bins > t
    int grand = tmp[255];
    int start = grand - tmp[t];
    for (int b = 0; b < SORT_BLOCKS; ++b) {
        blockOff[b * 256 + t] = start;
        start += blockHist[b * 256 + t];
    }
}

__global__ __launch_bounds__(256) void dscatter2_kernel(
    const int* __restrict__ rowptr, const int* __restrict__ blockOff,
    int* __restrict__ dperm, int N)
{
    __shared__ int cur[256];
    cur[threadIdx.x] = blockOff[blockIdx.x * 256 + threadIdx.x];
    __syncthreads();
    const int chunk = (N + SORT_BLOCKS - 1) / SORT_BLOCKS;
    const int lo = blockIdx.x * chunk;
    const int hi = (lo + chunk < N) ? lo + chunk : N;
    for (int d = lo + threadIdx.x; d < hi; d += 256) {
        int deg = rowptr[d + 1] - rowptr[d];
        int pos = atomicAdd(&cur[deg > 255 ? 255 : deg], 1);
        dperm[pos] = d;
    }
}

// ---------------- fused edge kernel: 4-lane group per (dst, head) ---------
// Head-major: xl bf16 [h][N][64], xr f32 [h][N][64]. gid = h*N + di.
template <int H, bool OUT_F32, bool OUT_BF16>
__global__ __launch_bounds__(256) void gat_fused4(
    const int* __restrict__ rowptr, const int* __restrict__ ssrc,
    const int* __restrict__ dperm,
    const unsigned short* __restrict__ xl, const float* __restrict__ xr,
    const float* __restrict__ att, const float* __restrict__ bias,
    float* __restrict__ outf, unsigned short* __restrict__ outb, int N)
{
    const int gid = blockIdx.x * 64 + (threadIdx.x >> 2);
    const int sub = threadIdx.x & 3;
    if (gid >= N * H) return;
    const int h  = gid / N;               // head-major ordering
    const int di = gid - h * N;
    const int d  = dperm[di];
    const int HC = H * 64;
    const int so = sub * 16;

    const unsigned short* xlh = xl + (size_t)h * N * 64;

    float xrv[16], attv[16], acc[16];
    {
        const float* pr = xr + ((size_t)h * N + d) * 64 + so;
        const float* pa = att + h * 64 + so;
        #pragma unroll
        for (int k = 0; k < 16; k += 4) {
            float4 v = *reinterpret_cast<const float4*>(pr + k);
            xrv[k] = v.x; xrv[k+1] = v.y; xrv[k+2] = v.z; xrv[k+3] = v.w;
            float4 w = *reinterpret_cast<const float4*>(pa + k);
            attv[k] = w.x; attv[k+1] = w.y; attv[k+2] = w.z; attv[k+3] = w.w;
        }
    }
    #pragma unroll
    for (int k = 0; k < 16; ++k) acc[k] = 0.f;
    float M = -3.0e38f, S = 0.f;

    const int begin = rowptr[d], end = rowptr[d + 1];
    uint4 c0, c1;
    {
        const unsigned short* pl = xlh + (size_t)ssrc[begin] * 64 + so;
        c0 = *reinterpret_cast<const uint4*>(pl);
        c1 = *reinterpret_cast<const uint4*>(pl + 8);
    }
    for (int e = begin; e < end; ++e) {
        uint4 n0, n1;
        const bool more = (e + 1 < end);
        if (more) {
            const unsigned short* pl = xlh + (size_t)ssrc[e + 1] * 64 + so;
            n0 = *reinterpret_cast<const uint4*>(pl);
            n1 = *reinterpret_cast<const uint4*>(pl + 8);
        }
        float cur[16];
        unpack8(c0, cur);
        unpack8(c1, cur + 8);
        float p = 0.f;
        #pragma unroll
        for (int k = 0; k < 16; ++k) {
            float v = cur[k] + xrv[k];
            v = fmaxf(v, 0.2f * v);           // leaky_relu 0.2
            p = fmaf(v, attv[k], p);
        }
        p += __shfl_xor(p, 1);
        p += __shfl_xor(p, 2);
        float nM = fmaxf(M, p);
        float scale = __expf(M - nM);
        float w = __expf(p - nM);
        S = fmaf(S, scale, w);
        #pragma unroll
        for (int k = 0; k < 16; ++k) acc[k] = fmaf(acc[k], scale, w * cur[k]);
        M = nM;
        if (more) { c0 = n0; c1 = n1; }
    }
    float inv = 1.f / S;
    const float* pb = bias + h * 64 + so;
    #pragma unroll
    for (int k = 0; k < 16; ++k) {
        float val = fmaf(acc[k], inv, pb[k]);
        acc[k] = val > 0.f ? val : 0.f;
    }
    size_t ob = (size_t)d * HC + h * 64 + so;    // node-major output (GEMM A)
    if (OUT_F32) {
        #pragma unroll
        for (int k = 0; k < 16; k += 4) {
            float4 v = {acc[k], acc[k+1], acc[k+2], acc[k+3]};
            *reinterpret_cast<float4*>(outf + ob + k) = v;
        }
    }
    if (OUT_BF16) {
        unsigned pk[8];
        #pragma unroll
        for (int k = 0; k < 8; ++k)
            pk[k] = (unsigned)f2bf(acc[2*k]) | ((unsigned)f2bf(acc[2*k+1]) << 16);
        uint4 lo = {pk[0], pk[1], pk[2], pk[3]};
        uint4 hi = {pk[4], pk[5], pk[6], pk[7]};
        *reinterpret_cast<uint4*>(outb + ob) = lo;
        *reinterpret_cast<uint4*>(outb + ob + 8) = hi;
    }
}

// ---------------- segmented pool (batch sorted) + counts ------------------
__global__ __launch_bounds__(256) void pool_kernel2(
    const float* __restrict__ h3, const int* __restrict__ batch,
    float* __restrict__ sums, float* __restrict__ counts, int N)
{
    const int wave = blockIdx.x * 4 + (threadIdx.x >> 6);
    const int lane = threadIdx.x & 63;
    const int n0 = wave * 64;
    if (n0 >= N) return;
    const int n1 = (n0 + 64 < N) ? n0 + 64 : N;
    float s = 0.f, cnt = 0.f;
    int g = batch[n0];
    for (int n = n0; n < n1; ++n) {
        int gn = batch[n];
        if (gn != g) {
            atomicAdd(&sums[g * 64 + lane], s);
            if (lane == 0) atomicAdd(&counts[g], cnt);
            s = 0.f; cnt = 0.f; g = gn;
        }
        s += h3[(size_t)n * 64 + lane];
        cnt += 1.f;
    }
    atomicAdd(&sums[g * 64 + lane], s);
    if (lane == 0) atomicAdd(&counts[g], cnt);
}

// ---------------- MLP ------------------------------------------------------
__global__ __launch_bounds__(64) void mlp_kernel(
    const float* __restrict__ sums, const float* __restrict__ counts,
    const float* __restrict__ Wm1, const float* __restrict__ bm1,
    const float* __restrict__ Wm2, const float* __restrict__ bm2,
    float* __restrict__ out)
{
    int g = blockIdx.x;
    int t = threadIdx.x;
    __shared__ float pooled[64];
    __shared__ float hidden[32];
    float cnt = counts[g];
    cnt = cnt > 1.f ? cnt : 1.f;
    pooled[t] = sums[g * 64 + t] / cnt;
    __syncthreads();
    if (t < 32) {
        float a = bm1[t];
        #pragma unroll
        for (int k = 0; k < 64; ++k) a = fmaf(pooled[k], Wm1[k * 32 + t], a);
        hidden[t] = a > 0.f ? a : 0.f;
    }
    __syncthreads();
    if (t < 2) {
        float a = bm2[t];
        #pragma unroll
        for (int j = 0; j < 32; ++j) a = fmaf(hidden[j], Wm2[j * 2 + t], a);
        out[g * 2 + t] = a;
    }
}

// ---------------- layer driver ---------------------------------------------
static void run_layer(const unsigned short* Xb, int K, int H,
                      const float* bl, const float* br,
                      const float* att, const float* bias_out,
                      const unsigned short* Wtl, const unsigned short* Wtr,
                      const int* rowptr, const int* ssrc, const int* dperm, int N,
                      unsigned short* xl, float* xr,
                      float* houtf, unsigned short* houtb,
                      hipStream_t stream)
{
    const int No = H * 64;
    dim3 g((N + 127) / 128, No / 64, 2);
    gemm_mfma<<<g, 256, 0, stream>>>(Xb, Wtl, Wtr, bl, br, xl, xr, N, No, K);

    int ngroups = N * H;
    int blocks = (ngroups + 63) / 64;
    if (H == 4)
        gat_fused4<4, false, true><<<blocks, 256, 0, stream>>>(
            rowptr, ssrc, dperm, xl, xr, att, bias_out, houtf, houtb, N);
    else if (H == 2)
        gat_fused4<2, false, true><<<blocks, 256, 0, stream>>>(
            rowptr, ssrc, dperm, xl, xr, att, bias_out, houtf, houtb, N);
    else
        gat_fused4<1, true, false><<<blocks, 256, 0, stream>>>(
            rowptr, ssrc, dperm, xl, xr, att, bias_out, houtf, houtb, N);
}

extern "C" void kernel_launch(void* const* d_in, const int* in_sizes, int n_in,
                              void* d_out, int out_size, void* d_ws, size_t ws_size,
                              hipStream_t stream)
{
    const float* x    = (const float*)d_in[0];
    const int*   ei   = (const int*)d_in[1];
    const int*   batch= (const int*)d_in[2];
    const float* Wl1 = (const float*)d_in[3];
    const float* bl1 = (const float*)d_in[4];
    const float* Wr1 = (const float*)d_in[5];
    const float* br1 = (const float*)d_in[6];
    const float* att1= (const float*)d_in[7];
    const float* b1  = (const float*)d_in[8];
    const float* Wl2 = (const float*)d_in[9];
    const float* bl2 = (const float*)d_in[10];
    const float* Wr2 = (const float*)d_in[11];
    const float* br2 = (const float*)d_in[12];
    const float* att2= (const float*)d_in[13];
    const float* b2  = (const float*)d_in[14];
    const float* Wl3 = (const float*)d_in[15];
    const float* bl3 = (const float*)d_in[16];
    const float* Wr3 = (const float*)d_in[17];
    const float* br3 = (const float*)d_in[18];
    const float* att3= (const float*)d_in[19];
    const float* b3  = (const float*)d_in[20];
    const float* Wm1 = (const float*)d_in[21];
    const float* bm1 = (const float*)d_in[22];
    const float* Wm2 = (const float*)d_in[23];
    const float* bm2 = (const float*)d_in[24];

    const int N    = in_sizes[2];          // 50000
    const int E    = in_sizes[1] / 2;      // 800000
    const int Etot = E + N;                // + self loops
    const int K1   = in_sizes[0] / N;      // 128

    // workspace layout
    char* wsb = (char*)d_ws;
    size_t o = 0;
    auto alloc = [&](size_t bytes) { char* p = wsb + o; o += (bytes + 255) & ~(size_t)255; return p; };
    unsigned short* xl    = (unsigned short*)alloc((size_t)N * 256 * 2);
    float*          xr    = (float*)alloc((size_t)N * 256 * 4);
    unsigned short* xb    = (unsigned short*)alloc((size_t)N * K1 * 2);
    unsigned short* h1b   = (unsigned short*)alloc((size_t)N * 256 * 2);
    unsigned short* h2b   = (unsigned short*)alloc((size_t)N * 128 * 2);
    float*          h3f   = (float*)alloc((size_t)N * 64 * 4);
    int*   deg    = (int*)alloc((size_t)N * 4);
    int*   rowptr = (int*)alloc((size_t)(N + 1) * 4);
    int*   cursor = (int*)alloc((size_t)N * 4);
    int*   ssrc   = (int*)alloc((size_t)Etot * 4);
    int*   dperm  = (int*)alloc((size_t)N * 4);
    int*   blockHist = (int*)alloc((size_t)SORT_BLOCKS * 256 * 4);
    int*   blockOff  = (int*)alloc((size_t)SORT_BLOCKS * 256 * 4);
    int*   blockSums = (int*)alloc((size_t)SCAN_BLOCKS * 4);
    int*   blockBase = (int*)alloc((size_t)SCAN_BLOCKS * 4);
    unsigned short* Wt1l = (unsigned short*)alloc(128 * 256 * 2);
    unsigned short* Wt1r = (unsigned short*)alloc(128 * 256 * 2);
    unsigned short* Wt2l = (unsigned short*)alloc(256 * 128 * 2);
    unsigned short* Wt2r = (unsigned short*)alloc(256 * 128 * 2);
    unsigned short* Wt3l = (unsigned short*)alloc(128 * 64 * 2);
    unsigned short* Wt3r = (unsigned short*)alloc(128 * 64 * 2);
    float* sums   = (float*)alloc(64 * 64 * 4);
    float* counts = (float*)alloc(64 * 4);
    (void)ws_size; (void)n_in; (void)out_size;

    // ---- CSR build + degree sort (shared by all 3 layers) ----
    hipMemsetAsync(deg, 0, (size_t)N * 4, stream);
    hist_kernel<<<(Etot + 255) / 256, 256, 0, stream>>>(ei, E, Etot, deg);
    scan1_kernel<<<SCAN_BLOCKS, 256, 0, stream>>>(deg, blockSums, N);
    scan2_kernel<<<1, 256, 0, stream>>>(blockSums, blockBase, rowptr, N);
    scan3_kernel<<<SCAN_BLOCKS, 256, 0, stream>>>(deg, blockBase, rowptr, cursor, N);
    scatter_kernel<<<(Etot + 255) / 256, 256, 0, stream>>>(ei, E, Etot, cursor, ssrc);
    dhist2_kernel<<<SORT_BLOCKS, 256, 0, stream>>>(rowptr, blockHist, N);
    dscan2_kernel<<<1, 256, 0, stream>>>(blockHist, blockOff);
    dscatter2_kernel<<<SORT_BLOCKS, 256, 0, stream>>>(rowptr, blockOff, dperm, N);

    // ---- convert input x + all weights to bf16 ----
    cvt_kernel<<<((N * K1) / 4 + 255) / 256, 256, 0, stream>>>(x, xb, N * K1);
    cvt_wt_all_kernel<<<(147456 + 255) / 256, 256, 0, stream>>>(
        Wl1, Wr1, Wt1l, Wt1r, Wl2, Wr2, Wt2l, Wt2r, Wl3, Wr3, Wt3l, Wt3r);

    // ---- layers ----
    run_layer(xb, K1, 4, bl1, br1, att1, b1, Wt1l, Wt1r,
              rowptr, ssrc, dperm, N, xl, xr, nullptr, h1b, stream);
    run_layer(h1b, 256, 2, bl2, br2, att2, b2, Wt2l, Wt2r,
              rowptr, ssrc, dperm, N, xl, xr, nullptr, h2b, stream);
    run_layer(h2b, 128, 1, bl3, br3, att3, b3, Wt3l, Wt3r,
              rowptr, ssrc, dperm, N, xl, xr, h3f, nullptr, stream);

    // ---- pool + MLP ----
    hipMemsetAsync(sums, 0, 64 * 64 * 4, stream);
    hipMemsetAsync(counts, 0, 64 * 4, stream);
    {
        int waves = (N + 63) / 64;
        pool_kernel2<<<(waves + 3) / 4, 256, 0, stream>>>(h3f, batch, sums, counts, N);
    }
    mlp_kernel<<<64, 64, 0, stream>>>(sums, counts, Wm1, bm1, Wm2, bm2, (float*)d_out);
}

// Round 8
// 357.206 us; speedup vs baseline: 8.0085x; 1.3154x over previous
//
#include <hip/hip_runtime.h>

// GATv2 GNN classifier.
// R8: GEMM rewritten as A-resident slab kernel (BM=64, A staged once in LDS,
// z/y/K-half loops inside, LDS-staged coalesced full-line epilogue) -> kills
// the 8x A re-fetch and the 3x write amplification seen in R7 counters.
// xr stored bf16 (halves GEMM write + edge read). Rest as R7.

typedef __attribute__((ext_vector_type(8))) short bf16x8;
typedef __attribute__((ext_vector_type(4))) float f32x4;

#define SORT_BLOCKS 64
#define SCAN_BLOCKS 256

__device__ inline unsigned short f2bf(float f) {
    unsigned u = __float_as_uint(f);
    unsigned r = (u + 0x7fff + ((u >> 16) & 1)) >> 16;   // RNE
    return (unsigned short)r;
}

__device__ inline void unpack8(uint4 a, float* d) {
    d[0] = __uint_as_float(a.x << 16); d[1] = __uint_as_float(a.x & 0xffff0000u);
    d[2] = __uint_as_float(a.y << 16); d[3] = __uint_as_float(a.y & 0xffff0000u);
    d[4] = __uint_as_float(a.z << 16); d[5] = __uint_as_float(a.z & 0xffff0000u);
    d[6] = __uint_as_float(a.w << 16); d[7] = __uint_as_float(a.w & 0xffff0000u);
}

// ---------------- fp32 -> bf16 elementwise convert ------------------------
__global__ void cvt_kernel(const float* __restrict__ in,
                           unsigned short* __restrict__ out, int n)
{
    int i = (blockIdx.x * blockDim.x + threadIdx.x) * 4;
    if (i >= n) return;
    float4 v = *reinterpret_cast<const float4*>(in + i);
    ushort4 o;
    o.x = f2bf(v.x); o.y = f2bf(v.y); o.z = f2bf(v.z); o.w = f2bf(v.w);
    *reinterpret_cast<ushort4*>(out + i) = o;
}

// ---------------- all six W [K][No] fp32 -> Wt [No][K] bf16, one launch ----
__global__ void cvt_wt_all_kernel(
    const float* __restrict__ Wl1, const float* __restrict__ Wr1, unsigned short* __restrict__ T1l, unsigned short* __restrict__ T1r,
    const float* __restrict__ Wl2, const float* __restrict__ Wr2, unsigned short* __restrict__ T2l, unsigned short* __restrict__ T2r,
    const float* __restrict__ Wl3, const float* __restrict__ Wr3, unsigned short* __restrict__ T3l, unsigned short* __restrict__ T3r)
{
    int id = blockIdx.x * blockDim.x + threadIdx.x;
    const float* W; unsigned short* T; int K, No, idx;
    if (id < 2 * 32768) {            // layer1: 128x256
        K = 128; No = 256; idx = id & 32767;
        W = (id < 32768) ? Wl1 : Wr1; T = (id < 32768) ? T1l : T1r;
    } else if (id < 2 * 32768 + 2 * 32768) {  // layer2: 256x128
        int v = id - 65536; K = 256; No = 128; idx = v & 32767;
        W = (v < 32768) ? Wl2 : Wr2; T = (v < 32768) ? T2l : T2r;
    } else {                          // layer3: 128x64
        int v = id - 131072; if (v >= 2 * 8192) return;
        K = 128; No = 64; idx = v & 8191;
        W = (v < 8192) ? Wl3 : Wr3; T = (v < 8192) ? T3l : T3r;
    }
    int n = idx / K, k = idx - n * K;
    T[idx] = f2bf(W[(size_t)k * No + n]);
}

// ---------------- A-resident slab GEMM -------------------------------------
// Block owns 64 A-rows; A LDS-resident across both weight matrices and all
// output columns. Outputs head-major bf16 [h][M][64], full-line coalesced.
template <int K, int NY>
__global__ __launch_bounds__(256) void gemm_slab(
    const unsigned short* __restrict__ A,     // [M][K] bf16
    const unsigned short* __restrict__ W0, const unsigned short* __restrict__ W1,
    const float* __restrict__ bias0, const float* __restrict__ bias1,
    unsigned short* __restrict__ OutL, unsigned short* __restrict__ OutR,
    int M)
{
    constexpr int CPR = K / 8;                 // 16B chunks per A row
    __shared__ __align__(16) char As[64 * K * 2];
    __shared__ __align__(16) char Bs[64 * 128 * 2];   // W k-half stage / C stage

    const int t = threadIdx.x;
    const int lane = t & 63;
    const int wid = t >> 6;
    const int row0 = blockIdx.x * 64;

    // ---- stage A slab (64 x K), swizzled ----
    #pragma unroll
    for (int i = 0; i < (64 * CPR) / 256; ++i) {
        int c16 = i * 256 + t;
        int r = c16 / CPR, j = c16 % CPR;
        int gr = row0 + r; if (gr > M - 1) gr = M - 1;
        uint4 v = *reinterpret_cast<const uint4*>(A + (size_t)gr * K + j * 8);
        *reinterpret_cast<uint4*>(As + r * (2 * K) + ((j ^ (r & 7)) << 4)) = v;
    }

    const int ra = wid * 16 + (lane & 15);
    const int rowA_byte = ra * (2 * K);

    for (int z = 0; z < 2; ++z) {
        const unsigned short* Wt = z ? W1 : W0;   // [NY*64][K]
        const float* bias = z ? bias1 : bias0;
        unsigned short* Out = z ? OutR : OutL;
        for (int y = 0; y < NY; ++y) {
            f32x4 acc[4];
            #pragma unroll
            for (int j = 0; j < 4; ++j) acc[j] = (f32x4){0.f, 0.f, 0.f, 0.f};

            #pragma unroll
            for (int kh = 0; kh < K / 128; ++kh) {
                __syncthreads();   // Bs free (also covers As on first pass)
                #pragma unroll
                for (int i = 0; i < 4; ++i) {   // stage W tile 64x128 bf16
                    int c16 = i * 256 + t;
                    int n = c16 >> 4, j = c16 & 15;
                    uint4 v = *reinterpret_cast<const uint4*>(
                        Wt + (size_t)(y * 64 + n) * K + kh * 128 + j * 8);
                    *reinterpret_cast<uint4*>(Bs + n * 256 + ((j ^ (n & 7)) << 4)) = v;
                }
                __syncthreads();
                #pragma unroll
                for (int ks = 0; ks < 4; ++ks) {
                    int chA = kh * 16 + ks * 4 + (lane >> 4);
                    bf16x8 a = *reinterpret_cast<const bf16x8*>(
                        As + rowA_byte + ((chA ^ (ra & 7)) << 4));
                    #pragma unroll
                    for (int j = 0; j < 4; ++j) {
                        int nb = j * 16 + (lane & 15);
                        int chB = ks * 4 + (lane >> 4);
                        bf16x8 b = *reinterpret_cast<const bf16x8*>(
                            Bs + nb * 256 + ((chB ^ (nb & 7)) << 4));
                        acc[j] = __builtin_amdgcn_mfma_f32_16x16x32_bf16(a, b, acc[j], 0, 0, 0);
                    }
                }
            }
            __syncthreads();            // all Bs reads done
            // stage C tile (64 rows x 128B) into Bs
            #pragma unroll
            for (int j = 0; j < 4; ++j) {
                float bb = bias[y * 64 + j * 16 + (lane & 15)];
                #pragma unroll
                for (int q = 0; q < 4; ++q) {
                    int r = wid * 16 + (lane >> 4) * 4 + q;
                    int c = j * 16 + (lane & 15);
                    *reinterpret_cast<unsigned short*>(Bs + r * 128 + c * 2)
                        = f2bf(acc[j][q] + bb);
                }
            }
            __syncthreads();
            // coalesced copy-out: head h == y, full 128B rows
            {
                int r = t >> 2, ch = t & 3;
                int gr = row0 + r;
                if (gr < M) {
                    const uint4* src = reinterpret_cast<const uint4*>(Bs + r * 128 + ch * 32);
                    uint4 v0 = src[0], v1 = src[1];
                    uint4* dst = reinterpret_cast<uint4*>(
                        Out + ((size_t)y * M + gr) * 64 + ch * 16);
                    dst[0] = v0; dst[1] = v1;
                }
            }
        }
    }
}

// ---------------- CSR build ------------------------------------------------
__global__ void hist_kernel(const int* __restrict__ ei, int E, int Etot,
                            int* __restrict__ deg)
{
    int i = blockIdx.x * blockDim.x + threadIdx.x;
    if (i >= Etot) return;
    int d = (i < E) ? ei[E + i] : (i - E);
    atomicAdd(&deg[d], 1);
}

// ---- 3-phase coalesced scan of deg[0..N) -> rowptr/cursor ----------------
__global__ __launch_bounds__(256) void scan1_kernel(
    const int* __restrict__ deg, int* __restrict__ blockSums, int N)
{
    __shared__ int red[256];
    const int b = blockIdx.x, t = threadIdx.x;
    const int chunk = (N + SCAN_BLOCKS - 1) / SCAN_BLOCKS;
    const int lo = b * chunk;
    const int hi = (lo + chunk < N) ? lo + chunk : N;
    int s = 0;
    for (int i = lo + t; i < hi; i += 256) s += deg[i];
    red[t] = s;
    __syncthreads();
    #pragma unroll
    for (int off = 128; off > 0; off >>= 1) {
        if (t < off) red[t] += red[t + off];
        __syncthreads();
    }
    if (t == 0) blockSums[b] = red[0];
}

__global__ __launch_bounds__(256) void scan2_kernel(
    const int* __restrict__ blockSums, int* __restrict__ blockBase,
    int* __restrict__ rowptr, int N)
{
    __shared__ int tmp[256];
    const int t = threadIdx.x;
    int v = blockSums[t];
    tmp[t] = v;
    __syncthreads();
    for (int off = 1; off < 256; off <<= 1) {
        int u = (t >= off) ? tmp[t - off] : 0;
        __syncthreads();
        tmp[t] += u;
        __syncthreads();
    }
    blockBase[t] = tmp[t] - v;        // exclusive
    if (t == 255) rowptr[N] = tmp[255];
}

__global__ __launch_bounds__(256) void scan3_kernel(
    const int* __restrict__ deg, const int* __restrict__ blockBase,
    int* __restrict__ rowptr, int* __restrict__ cursor, int N)
{
    __shared__ int tmp[256];
    __shared__ int carry;
    const int b = blockIdx.x, t = threadIdx.x;
    const int chunk = (N + SCAN_BLOCKS - 1) / SCAN_BLOCKS;
    const int lo = b * chunk;
    const int hi = (lo + chunk < N) ? lo + chunk : N;
    if (t == 0) carry = blockBase[b];
    __syncthreads();
    for (int j = lo; j < hi; j += 256) {
        int i = j + t;
        int v = (i < hi) ? deg[i] : 0;
        tmp[t] = v;
        __syncthreads();
        for (int off = 1; off < 256; off <<= 1) {
            int u = (t >= off) ? tmp[t - off] : 0;
            __syncthreads();
            tmp[t] += u;
            __syncthreads();
        }
        int excl = carry + tmp[t] - v;
        if (i < hi) { rowptr[i] = excl; cursor[i] = excl; }
        __syncthreads();
        if (t == 255) carry += tmp[255];
        __syncthreads();
    }
}

__global__ void scatter_kernel(const int* __restrict__ ei, int E, int Etot,
                               int* __restrict__ cursor, int* __restrict__ ssrc)
{
    int i = blockIdx.x * blockDim.x + threadIdx.x;
    if (i >= Etot) return;
    int d, s;
    if (i < E) { s = ei[i]; d = ei[E + i]; }
    else       { s = i - E; d = s; }
    int pos = atomicAdd(&cursor[d], 1);
    ssrc[pos] = s;
}

// ---------------- degree sort (DESCENDING), contention-free ---------------
__global__ __launch_bounds__(256) void dhist2_kernel(
    const int* __restrict__ rowptr, int* __restrict__ blockHist, int N)
{
    __shared__ int lh[256];
    lh[threadIdx.x] = 0;
    __syncthreads();
    const int chunk = (N + SORT_BLOCKS - 1) / SORT_BLOCKS;
    const int lo = blockIdx.x * chunk;
    const int hi = (lo + chunk < N) ? lo + chunk : N;
    for (int d = lo + threadIdx.x; d < hi; d += 256) {
        int deg = rowptr[d + 1] - rowptr[d];
        atomicAdd(&lh[deg > 255 ? 255 : deg], 1);
    }
    __syncthreads();
    blockHist[blockIdx.x * 256 + threadIdx.x] = lh[threadIdx.x];
}

__global__ __launch_bounds__(256) void dscan2_kernel(
    const int* __restrict__ blockHist, int* __restrict__ blockOff)
{
    const int t = threadIdx.x;          // t = bin
    int total = 0;
    for (int b = 0; b < SORT_BLOCKS; ++b) total += blockHist[b * 256 + t];
    __shared__ int tmp[256];
    tmp[t] = total;
    __syncthreads();
    for (int off = 1; off < 256; off <<= 1) {
        int v = (t >= off) ? tmp[t - off] : 0;
        __syncthreads();
        tmp[t] += v;
        __syncthreads();
    }
    int grand = tmp[255];
    int start = grand - tmp[t];       // descending
    for (int b = 0; b < SORT_BLOCKS; ++b) {
        blockOff[b * 256 + t] = start;
        start += blockHist[b * 256 + t];
    }
}

__global__ __launch_bounds__(256) void dscatter2_kernel(
    const int* __restrict__ rowptr, const int* __restrict__ blockOff,
    int* __restrict__ dperm, int N)
{
    __shared__ int cur[256];
    cur[threadIdx.x] = blockOff[blockIdx.x * 256 + threadIdx.x];
    __syncthreads();
    const int chunk = (N + SORT_BLOCKS - 1) / SORT_BLOCKS;
    const int lo = blockIdx.x * chunk;
    const int hi = (lo + chunk < N) ? lo + chunk : N;
    for (int d = lo + threadIdx.x; d < hi; d += 256) {
        int deg = rowptr[d + 1] - rowptr[d];
        int pos = atomicAdd(&cur[deg > 255 ? 255 : deg], 1);
        dperm[pos] = d;
    }
}

// ---------------- fused edge kernel: 4-lane group per (dst, head) ---------
// Head-major: xl bf16 [h][N][64], xr bf16 [h][N][64]. gid = h*N + di.
template <int H, bool OUT_F32, bool OUT_BF16>
__global__ __launch_bounds__(256) void gat_fused4(
    const int* __restrict__ rowptr, const int* __restrict__ ssrc,
    const int* __restrict__ dperm,
    const unsigned short* __restrict__ xl, const unsigned short* __restrict__ xr,
    const float* __restrict__ att, const float* __restrict__ bias,
    float* __restrict__ outf, unsigned short* __restrict__ outb, int N)
{
    const int gid = blockIdx.x * 64 + (threadIdx.x >> 2);
    const int sub = threadIdx.x & 3;
    if (gid >= N * H) return;
    const int h  = gid / N;               // head-major ordering
    const int di = gid - h * N;
    const int d  = dperm[di];
    const int HC = H * 64;
    const int so = sub * 16;

    const unsigned short* xlh = xl + (size_t)h * N * 64;

    float xrv[16], attv[16], acc[16];
    {
        const unsigned short* pr = xr + ((size_t)h * N + d) * 64 + so;
        uint4 v0 = *reinterpret_cast<const uint4*>(pr);
        uint4 v1 = *reinterpret_cast<const uint4*>(pr + 8);
        unpack8(v0, xrv); unpack8(v1, xrv + 8);
        const float* pa = att + h * 64 + so;
        #pragma unroll
        for (int k = 0; k < 16; k += 4) {
            float4 w = *reinterpret_cast<const float4*>(pa + k);
            attv[k] = w.x; attv[k+1] = w.y; attv[k+2] = w.z; attv[k+3] = w.w;
        }
    }
    #pragma unroll
    for (int k = 0; k < 16; ++k) acc[k] = 0.f;
    float M = -3.0e38f, S = 0.f;

    const int begin = rowptr[d], end = rowptr[d + 1];
    uint4 c0, c1;
    {
        const unsigned short* pl = xlh + (size_t)ssrc[begin] * 64 + so;
        c0 = *reinterpret_cast<const uint4*>(pl);
        c1 = *reinterpret_cast<const uint4*>(pl + 8);
    }
    for (int e = begin; e < end; ++e) {
        uint4 n0, n1;
        const bool more = (e + 1 < end);
        if (more) {
            const unsigned short* pl = xlh + (size_t)ssrc[e + 1] * 64 + so;
            n0 = *reinterpret_cast<const uint4*>(pl);
            n1 = *reinterpret_cast<const uint4*>(pl + 8);
        }
        float cur[16];
        unpack8(c0, cur);
        unpack8(c1, cur + 8);
        float p = 0.f;
        #pragma unroll
        for (int k = 0; k < 16; ++k) {
            float v = cur[k] + xrv[k];
            v = fmaxf(v, 0.2f * v);           // leaky_relu 0.2
            p = fmaf(v, attv[k], p);
        }
        p += __shfl_xor(p, 1);
        p += __shfl_xor(p, 2);
        float nM = fmaxf(M, p);
        float scale = __expf(M - nM);
        float w = __expf(p - nM);
        S = fmaf(S, scale, w);
        #pragma unroll
        for (int k = 0; k < 16; ++k) acc[k] = fmaf(acc[k], scale, w * cur[k]);
        M = nM;
        if (more) { c0 = n0; c1 = n1; }
    }
    float inv = 1.f / S;
    const float* pb = bias + h * 64 + so;
    #pragma unroll
    for (int k = 0; k < 16; ++k) {
        float val = fmaf(acc[k], inv, pb[k]);
        acc[k] = val > 0.f ? val : 0.f;
    }
    size_t ob = (size_t)d * HC + h * 64 + so;    // node-major output (GEMM A)
    if (OUT_F32) {
        #pragma unroll
        for (int k = 0; k < 16; k += 4) {
            float4 v = {acc[k], acc[k+1], acc[k+2], acc[k+3]};
            *reinterpret_cast<float4*>(outf + ob + k) = v;
        }
    }
    if (OUT_BF16) {
        unsigned pk[8];
        #pragma unroll
        for (int k = 0; k < 8; ++k)
            pk[k] = (unsigned)f2bf(acc[2*k]) | ((unsigned)f2bf(acc[2*k+1]) << 16);
        uint4 lo = {pk[0], pk[1], pk[2], pk[3]};
        uint4 hi = {pk[4], pk[5], pk[6], pk[7]};
        *reinterpret_cast<uint4*>(outb + ob) = lo;
        *reinterpret_cast<uint4*>(outb + ob + 8) = hi;
    }
}

// ---------------- segmented pool (batch sorted) + counts ------------------
__global__ __launch_bounds__(256) void pool_kernel2(
    const float* __restrict__ h3, const int* __restrict__ batch,
    float* __restrict__ sums, float* __restrict__ counts, int N)
{
    const int wave = blockIdx.x * 4 + (threadIdx.x >> 6);
    const int lane = threadIdx.x & 63;
    const int n0 = wave * 64;
    if (n0 >= N) return;
    const int n1 = (n0 + 64 < N) ? n0 + 64 : N;
    float s = 0.f, cnt = 0.f;
    int g = batch[n0];
    for (int n = n0; n < n1; ++n) {
        int gn = batch[n];
        if (gn != g) {
            atomicAdd(&sums[g * 64 + lane], s);
            if (lane == 0) atomicAdd(&counts[g], cnt);
            s = 0.f; cnt = 0.f; g = gn;
        }
        s += h3[(size_t)n * 64 + lane];
        cnt += 1.f;
    }
    atomicAdd(&sums[g * 64 + lane], s);
    if (lane == 0) atomicAdd(&counts[g], cnt);
}

// ---------------- MLP ------------------------------------------------------
__global__ __launch_bounds__(64) void mlp_kernel(
    const float* __restrict__ sums, const float* __restrict__ counts,
    const float* __restrict__ Wm1, const float* __restrict__ bm1,
    const float* __restrict__ Wm2, const float* __restrict__ bm2,
    float* __restrict__ out)
{
    int g = blockIdx.x;
    int t = threadIdx.x;
    __shared__ float pooled[64];
    __shared__ float hidden[32];
    float cnt = counts[g];
    cnt = cnt > 1.f ? cnt : 1.f;
    pooled[t] = sums[g * 64 + t] / cnt;
    __syncthreads();
    if (t < 32) {
        float a = bm1[t];
        #pragma unroll
        for (int k = 0; k < 64; ++k) a = fmaf(pooled[k], Wm1[k * 32 + t], a);
        hidden[t] = a > 0.f ? a : 0.f;
    }
    __syncthreads();
    if (t < 2) {
        float a = bm2[t];
        #pragma unroll
        for (int j = 0; j < 32; ++j) a = fmaf(hidden[j], Wm2[j * 2 + t], a);
        out[g * 2 + t] = a;
    }
}

// ---------------- layer driver ---------------------------------------------
static void run_layer(const unsigned short* Xb, int K, int H,
                      const float* bl, const float* br,
                      const float* att, const float* bias_out,
                      const unsigned short* Wtl, const unsigned short* Wtr,
                      const int* rowptr, const int* ssrc, const int* dperm, int N,
                      unsigned short* xl, unsigned short* xr,
                      float* houtf, unsigned short* houtb,
                      hipStream_t stream)
{
    int gblocks = (N + 63) / 64;
    if (K == 128 && H == 4)
        gemm_slab<128, 4><<<gblocks, 256, 0, stream>>>(Xb, Wtl, Wtr, bl, br, xl, xr, N);
    else if (K == 256)
        gemm_slab<256, 2><<<gblocks, 256, 0, stream>>>(Xb, Wtl, Wtr, bl, br, xl, xr, N);
    else
        gemm_slab<128, 1><<<gblocks, 256, 0, stream>>>(Xb, Wtl, Wtr, bl, br, xl, xr, N);

    int ngroups = N * H;
    int blocks = (ngroups + 63) / 64;
    if (H == 4)
        gat_fused4<4, false, true><<<blocks, 256, 0, stream>>>(
            rowptr, ssrc, dperm, xl, xr, att, bias_out, houtf, houtb, N);
    else if (H == 2)
        gat_fused4<2, false, true><<<blocks, 256, 0, stream>>>(
            rowptr, ssrc, dperm, xl, xr, att, bias_out, houtf, houtb, N);
    else
        gat_fused4<1, true, false><<<blocks, 256, 0, stream>>>(
            rowptr, ssrc, dperm, xl, xr, att, bias_out, houtf, houtb, N);
}

extern "C" void kernel_launch(void* const* d_in, const int* in_sizes, int n_in,
                              void* d_out, int out_size, void* d_ws, size_t ws_size,
                              hipStream_t stream)
{
    const float* x    = (const float*)d_in[0];
    const int*   ei   = (const int*)d_in[1];
    const int*   batch= (const int*)d_in[2];
    const float* Wl1 = (const float*)d_in[3];
    const float* bl1 = (const float*)d_in[4];
    const float* Wr1 = (const float*)d_in[5];
    const float* br1 = (const float*)d_in[6];
    const float* att1= (const float*)d_in[7];
    const float* b1  = (const float*)d_in[8];
    const float* Wl2 = (const float*)d_in[9];
    const float* bl2 = (const float*)d_in[10];
    const float* Wr2 = (const float*)d_in[11];
    const float* br2 = (const float*)d_in[12];
    const float* att2= (const float*)d_in[13];
    const float* b2  = (const float*)d_in[14];
    const float* Wl3 = (const float*)d_in[15];
    const float* bl3 = (const float*)d_in[16];
    const float* Wr3 = (const float*)d_in[17];
    const float* br3 = (const float*)d_in[18];
    const float* att3= (const float*)d_in[19];
    const float* b3  = (const float*)d_in[20];
    const float* Wm1 = (const float*)d_in[21];
    const float* bm1 = (const float*)d_in[22];
    const float* Wm2 = (const float*)d_in[23];
    const float* bm2 = (const float*)d_in[24];

    const int N    = in_sizes[2];          // 50000
    const int E    = in_sizes[1] / 2;      // 800000
    const int Etot = E + N;                // + self loops
    const int K1   = in_sizes[0] / N;      // 128

    // workspace layout
    char* wsb = (char*)d_ws;
    size_t o = 0;
    auto alloc = [&](size_t bytes) { char* p = wsb + o; o += (bytes + 255) & ~(size_t)255; return p; };
    unsigned short* xl    = (unsigned short*)alloc((size_t)N * 256 * 2);
    unsigned short* xr    = (unsigned short*)alloc((size_t)N * 256 * 2);
    unsigned short* xb    = (unsigned short*)alloc((size_t)N * K1 * 2);
    unsigned short* h1b   = (unsigned short*)alloc((size_t)N * 256 * 2);
    unsigned short* h2b   = (unsigned short*)alloc((size_t)N * 128 * 2);
    float*          h3f   = (float*)alloc((size_t)N * 64 * 4);
    int*   deg    = (int*)alloc((size_t)N * 4);
    int*   rowptr = (int*)alloc((size_t)(N + 1) * 4);
    int*   cursor = (int*)alloc((size_t)N * 4);
    int*   ssrc   = (int*)alloc((size_t)Etot * 4);
    int*   dperm  = (int*)alloc((size_t)N * 4);
    int*   blockHist = (int*)alloc((size_t)SORT_BLOCKS * 256 * 4);
    int*   blockOff  = (int*)alloc((size_t)SORT_BLOCKS * 256 * 4);
    int*   blockSums = (int*)alloc((size_t)SCAN_BLOCKS * 4);
    int*   blockBase = (int*)alloc((size_t)SCAN_BLOCKS * 4);
    unsigned short* Wt1l = (unsigned short*)alloc(128 * 256 * 2);
    unsigned short* Wt1r = (unsigned short*)alloc(128 * 256 * 2);
    unsigned short* Wt2l = (unsigned short*)alloc(256 * 128 * 2);
    unsigned short* Wt2r = (unsigned short*)alloc(256 * 128 * 2);
    unsigned short* Wt3l = (unsigned short*)alloc(128 * 64 * 2);
    unsigned short* Wt3r = (unsigned short*)alloc(128 * 64 * 2);
    float* sums   = (float*)alloc(64 * 64 * 4);
    float* counts = (float*)alloc(64 * 4);
    (void)ws_size; (void)n_in; (void)out_size;

    // ---- CSR build + degree sort (shared by all 3 layers) ----
    hipMemsetAsync(deg, 0, (size_t)N * 4, stream);
    hist_kernel<<<(Etot + 255) / 256, 256, 0, stream>>>(ei, E, Etot, deg);
    scan1_kernel<<<SCAN_BLOCKS, 256, 0, stream>>>(deg, blockSums, N);
    scan2_kernel<<<1, 256, 0, stream>>>(blockSums, blockBase, rowptr, N);
    scan3_kernel<<<SCAN_BLOCKS, 256, 0, stream>>>(deg, blockBase, rowptr, cursor, N);
    scatter_kernel<<<(Etot + 255) / 256, 256, 0, stream>>>(ei, E, Etot, cursor, ssrc);
    dhist2_kernel<<<SORT_BLOCKS, 256, 0, stream>>>(rowptr, blockHist, N);
    dscan2_kernel<<<1, 256, 0, stream>>>(blockHist, blockOff);
    dscatter2_kernel<<<SORT_BLOCKS, 256, 0, stream>>>(rowptr, blockOff, dperm, N);

    // ---- convert input x + all weights to bf16 ----
    cvt_kernel<<<((N * K1) / 4 + 255) / 256, 256, 0, stream>>>(x, xb, N * K1);
    cvt_wt_all_kernel<<<(147456 + 255) / 256, 256, 0, stream>>>(
        Wl1, Wr1, Wt1l, Wt1r, Wl2, Wr2, Wt2l, Wt2r, Wl3, Wr3, Wt3l, Wt3r);

    // ---- layers ----
    run_layer(xb, K1, 4, bl1, br1, att1, b1, Wt1l, Wt1r,
              rowptr, ssrc, dperm, N, xl, xr, nullptr, h1b, stream);
    run_layer(h1b, 256, 2, bl2, br2, att2, b2, Wt2l, Wt2r,
              rowptr, ssrc, dperm, N, xl, xr, nullptr, h2b, stream);
    run_layer(h2b, 128, 1, bl3, br3, att3, b3, Wt3l, Wt3r,
              rowptr, ssrc, dperm, N, xl, xr, h3f, nullptr, stream);

    // ---- pool + MLP ----
    hipMemsetAsync(sums, 0, 64 * 64 * 4, stream);
    hipMemsetAsync(counts, 0, 64 * 4, stream);
    {
        int waves = (N + 63) / 64;
        pool_kernel2<<<(waves + 3) / 4, 256, 0, stream>>>(h3f, batch, sums, counts, N);
    }
    mlp_kernel<<<64, 64, 0, stream>>>(sums, counts, Wm1, bm1, Wm2, bm2, (float*)d_out);
}